// Round 6
// baseline (20614.331 us; speedup 1.0000x reference)
//
#include <hip/hip_runtime.h>
#include <hip/hip_bf16.h>

#define BB_ 16
#define T_ 2048
#define DIN_ 64
#define D_ 512
#define DI_ 1024
#define N_ 16
#define DC_ 4
#define R_ 32
#define L_ 3
#define DOUT_ 128

typedef __attribute__((ext_vector_type(8))) _Float16 f16x8;
typedef __attribute__((ext_vector_type(4))) float f32x4;

__device__ __forceinline__ float silu_f(float x) { return x / (1.f + __expf(-x)); }

__device__ __forceinline__ unsigned short f2h(float f) {
    union { _Float16 h; unsigned short u; } c;
    c.h = (_Float16)f;   // RNE
    return c.u;
}

// decode scale from amax bits: s = 2^(11 - e), so s*amax in [2^11, 2^12)
__device__ __forceinline__ float decode_scale(unsigned int bits) {
    if (bits == 0u) return 1.f;
    const int E = (int)(bits >> 23) & 0xFF;
    return __uint_as_float((unsigned)(265 - E) << 23);
}

// grid-stride absmax (float4) -> atomicMax on float bits (nonneg floats
// compare as uints). Deterministic: max is order-independent.
__global__ __launch_bounds__(256) void amax_kernel(
    const float* __restrict__ in, size_t n4, unsigned int* __restrict__ slot)
{
    float m = 0.f;
    for (size_t i = (size_t)blockIdx.x * 256 + threadIdx.x; i < n4;
         i += (size_t)gridDim.x * 256) {
        const float4 v = ((const float4*)in)[i];
        m = fmaxf(m, fmaxf(fmaxf(fabsf(v.x), fabsf(v.y)),
                           fmaxf(fabsf(v.z), fabsf(v.w))));
    }
#pragma unroll
    for (int off = 32; off; off >>= 1) m = fmaxf(m, __shfl_down(m, off));
    __shared__ float sm[4];
    if ((threadIdx.x & 63) == 0) sm[threadIdx.x >> 6] = m;
    __syncthreads();
    if (threadIdx.x == 0) {
        const float b = fmaxf(fmaxf(sm[0], sm[1]), fmaxf(sm[2], sm[3]));
        atomicMax(slot, __float_as_uint(b));
    }
}

// fp32 -> f16 with power-of-2 scale from slot (n multiple of 1024)
__global__ __launch_bounds__(256) void cast_scale_kernel(
    const float* __restrict__ in, unsigned short* __restrict__ out,
    const unsigned int* __restrict__ slot)
{
    const float s = decode_scale(*slot);
    const size_t i = ((size_t)blockIdx.x * 256 + threadIdx.x) * 4;
    const float4 v = *(const float4*)(in + i);
    *(ushort4*)(out + i) = make_ushort4(f2h(v.x * s), f2h(v.y * s),
                                        f2h(v.z * s), f2h(v.w * s));
}

// ---------------- scaled f16 MFMA GEMM: C = (A @ B^T) * inv ----------------
// 128x128 tile, BK=32, 4 waves (2x2), per-wave 64x64 = 4x4 frags of 16x16x32.
// ACT: 0 = none, 3 = +bias then tanh. Output fp32.
template<int ACT>
__global__ __launch_bounds__(256) void gemm_f16_t128(
    const unsigned short* __restrict__ A, int lda,
    const unsigned short* __restrict__ B, int ldb,
    const float* __restrict__ bias,
    float* __restrict__ C, int ldc, int K,
    const unsigned int* __restrict__ sa, const unsigned int* __restrict__ sb)
{
    __shared__ __align__(16) unsigned short As[128 * 32];
    __shared__ __align__(16) unsigned short Bs[128 * 32];
    const int tid  = threadIdx.x;
    const int lane = tid & 63;
    const int w    = tid >> 6;
    const int wr   = (w >> 1) << 6;
    const int wc   = (w & 1) << 6;
    const int l15  = lane & 15, l4 = lane >> 4;
    const int row0 = blockIdx.y << 7, col0 = blockIdx.x << 7;
    const int tq   = tid >> 2;
    const int tr   = (tid & 3) << 3;

    const float inv = (1.f / decode_scale(*sa)) * (1.f / decode_scale(*sb));

    f32x4 acc[4][4];
#pragma unroll
    for (int m = 0; m < 4; ++m)
#pragma unroll
        for (int n = 0; n < 4; ++n) acc[m][n] = (f32x4){0.f, 0.f, 0.f, 0.f};

    for (int k0 = 0; k0 < K; k0 += 32) {
        const uint4 av0 = *(const uint4*)(A + (size_t)(row0 + tq) * lda + k0 + tr);
        const uint4 av1 = *(const uint4*)(A + (size_t)(row0 + 64 + tq) * lda + k0 + tr);
        const uint4 bv0 = *(const uint4*)(B + (size_t)(col0 + tq) * ldb + k0 + tr);
        const uint4 bv1 = *(const uint4*)(B + (size_t)(col0 + 64 + tq) * ldb + k0 + tr);
        __syncthreads();
        *(uint4*)&As[tq * 32 + tr]        = av0;
        *(uint4*)&As[(64 + tq) * 32 + tr] = av1;
        *(uint4*)&Bs[tq * 32 + tr]        = bv0;
        *(uint4*)&Bs[(64 + tq) * 32 + tr] = bv1;
        __syncthreads();

        f16x8 af[4], bfr[4];
#pragma unroll
        for (int m = 0; m < 4; ++m)
            af[m] = *(const f16x8*)&As[(wr + m * 16 + l15) * 32 + l4 * 8];
#pragma unroll
        for (int n = 0; n < 4; ++n)
            bfr[n] = *(const f16x8*)&Bs[(wc + n * 16 + l15) * 32 + l4 * 8];
#pragma unroll
        for (int m = 0; m < 4; ++m)
#pragma unroll
            for (int n = 0; n < 4; ++n)
                acc[m][n] = __builtin_amdgcn_mfma_f32_16x16x32_f16(
                    af[m], bfr[n], acc[m][n], 0, 0, 0);
    }

#pragma unroll
    for (int n = 0; n < 4; ++n) {
        const int col = col0 + wc + n * 16 + l15;
        float bc = 0.f;
        if (ACT == 3) bc = bias[col];
#pragma unroll
        for (int m = 0; m < 4; ++m) {
            const int rowb = row0 + wr + m * 16 + (l4 << 2);
#pragma unroll
            for (int r = 0; r < 4; ++r) {
                float v = acc[m][n][r] * inv;
                if (ACT == 3) v = tanhf(v + bc);
                C[(size_t)(rowb + r) * ldc + col] = v;
            }
        }
    }
}

// ---------------- fp32 vector GEMM (small shapes) ----------------
// ACT: 0 none, 1 +bias, 2 +bias softplus.
template<int ACT>
__global__ __launch_bounds__(256) void gemm_t128(
    const float* __restrict__ A, int lda,
    const float* __restrict__ B, int ldb,
    const float* __restrict__ bias,
    float* __restrict__ C, int ldc, int K)
{
    __shared__ __align__(16) float As[8][128];
    __shared__ __align__(16) float Bs[8][128];
    const int tid  = threadIdx.x;
    const int row0 = blockIdx.y << 7;
    const int col0 = blockIdx.x << 7;
    const int tx = tid & 15, ty = tid >> 4;

    float acc[8][8];
#pragma unroll
    for (int i = 0; i < 8; ++i)
#pragma unroll
        for (int j = 0; j < 8; ++j) acc[i][j] = 0.f;

    const int arow = tid >> 1;
    const int acol = (tid & 1) << 2;
    const float* Ap = A + (size_t)(row0 + arow) * lda + acol;
    const float* Bp = B + (size_t)(col0 + arow) * ldb + acol;

    for (int k0 = 0; k0 < K; k0 += 8) {
        const float4 av = *(const float4*)(Ap + k0);
        const float4 bv = *(const float4*)(Bp + k0);
        __syncthreads();
        As[acol + 0][arow] = av.x; As[acol + 1][arow] = av.y;
        As[acol + 2][arow] = av.z; As[acol + 3][arow] = av.w;
        Bs[acol + 0][arow] = bv.x; Bs[acol + 1][arow] = bv.y;
        Bs[acol + 2][arow] = bv.z; Bs[acol + 3][arow] = bv.w;
        __syncthreads();
#pragma unroll
        for (int k = 0; k < 8; ++k) {
            float a[8], b[8];
            *(float4*)&a[0] = *(const float4*)&As[k][ty << 3];
            *(float4*)&a[4] = *(const float4*)&As[k][(ty << 3) + 4];
            *(float4*)&b[0] = *(const float4*)&Bs[k][tx << 3];
            *(float4*)&b[4] = *(const float4*)&Bs[k][(tx << 3) + 4];
#pragma unroll
            for (int i = 0; i < 8; ++i)
#pragma unroll
                for (int j = 0; j < 8; ++j)
                    acc[i][j] = fmaf(a[i], b[j], acc[i][j]);
        }
    }

    float bv8[8];
#pragma unroll
    for (int j = 0; j < 8; ++j) bv8[j] = (ACT >= 1) ? bias[col0 + (tx << 3) + j] : 0.f;

#pragma unroll
    for (int i = 0; i < 8; ++i) {
        float v[8];
#pragma unroll
        for (int j = 0; j < 8; ++j) {
            float t = (ACT >= 1) ? (acc[i][j] + bv8[j]) : acc[i][j];
            if (ACT == 2) t = (t > 20.f) ? t : log1pf(__expf(t));
            v[j] = t;
        }
        float* Cp = C + (size_t)(row0 + (ty << 3) + i) * ldc + col0 + (tx << 3);
        *(float4*)(Cp)     = make_float4(v[0], v[1], v[2], v[3]);
        *(float4*)(Cp + 4) = make_float4(v[4], v[5], v[6], v[7]);
    }
}

// 128x64 tile fp32 variant for N=64 (dbc GEMM)
__global__ __launch_bounds__(256) void gemm_t64n(
    const float* __restrict__ A, int lda,
    const float* __restrict__ B, int ldb,
    float* __restrict__ C, int ldc, int K)
{
    __shared__ __align__(16) float As[8][128];
    __shared__ __align__(16) float Bs[8][64];
    const int tid  = threadIdx.x;
    const int row0 = blockIdx.y << 7;
    const int col0 = blockIdx.x << 6;
    const int tx = tid & 15, ty = tid >> 4;

    float acc[8][4];
#pragma unroll
    for (int i = 0; i < 8; ++i)
#pragma unroll
        for (int j = 0; j < 4; ++j) acc[i][j] = 0.f;

    const int arow = tid >> 1, acol = (tid & 1) << 2;
    const int brow = tid >> 2, bcol = (tid & 3) << 1;
    const float* Ap = A + (size_t)(row0 + arow) * lda + acol;
    const float* Bp = B + (size_t)(col0 + brow) * ldb + bcol;

    for (int k0 = 0; k0 < K; k0 += 8) {
        const float4 av = *(const float4*)(Ap + k0);
        const float2 bv = *(const float2*)(Bp + k0);
        __syncthreads();
        As[acol + 0][arow] = av.x; As[acol + 1][arow] = av.y;
        As[acol + 2][arow] = av.z; As[acol + 3][arow] = av.w;
        Bs[bcol + 0][brow] = bv.x;
        Bs[bcol + 1][brow] = bv.y;
        __syncthreads();
#pragma unroll
        for (int k = 0; k < 8; ++k) {
            float a[8], b[4];
            *(float4*)&a[0] = *(const float4*)&As[k][ty << 3];
            *(float4*)&a[4] = *(const float4*)&As[k][(ty << 3) + 4];
            *(float4*)&b[0] = *(const float4*)&Bs[k][tx << 2];
#pragma unroll
            for (int i = 0; i < 8; ++i)
#pragma unroll
                for (int j = 0; j < 4; ++j)
                    acc[i][j] = fmaf(a[i], b[j], acc[i][j]);
        }
    }

#pragma unroll
    for (int i = 0; i < 8; ++i) {
        float* Cp = C + (size_t)(row0 + (ty << 3) + i) * ldc + col0 + (tx << 2);
        *(float4*)(Cp) = make_float4(acc[i][0], acc[i][1], acc[i][2], acc[i][3]);
    }
}

// depthwise causal conv (DC=4) + bias + SiLU. Reads xin = xz[:, :DI_].
__global__ __launch_bounds__(256) void conv_silu_kernel(
    const float* __restrict__ xz, const float* __restrict__ cw,
    const float* __restrict__ cb, float* __restrict__ u)
{
    const size_t idx = (size_t)blockIdx.x * 256 + threadIdx.x; // m*DI + c
    const int c = (int)(idx & (DI_ - 1));
    const size_t m = idx >> 10;
    const int t = (int)(m & (T_ - 1));
    const float w0 = cw[c * DC_ + 0], w1 = cw[c * DC_ + 1];
    const float w2 = cw[c * DC_ + 2], w3 = cw[c * DC_ + 3];
    const float* xr = xz + m * 2048 + c;
    float acc = cb[c];
    if (t >= 3) acc = fmaf(xr[-3 * 2048], w0, acc);
    if (t >= 2) acc = fmaf(xr[-2 * 2048], w1, acc);
    if (t >= 1) acc = fmaf(xr[-1 * 2048], w2, acc);
    acc = fmaf(xr[0], w3, acc);
    u[idx] = silu_f(acc);
}

// selective scan: thread owns (b, d); 16 states in registers; B/C staged in LDS.
// delta at xz[m*2048 + d] (in-place over xin), z at xz[m*2048 + 1024 + d].
// Fuses y += u*Dp and g = y*silu(z); writes g (fp32).
#define TC_ 128
__global__ __launch_bounds__(256) void scan_kernel(
    const float* __restrict__ u, const float* __restrict__ xz,
    const float* __restrict__ dbc, const float* __restrict__ A_log_l,
    const float* __restrict__ Dp_l, float* __restrict__ g)
{
    __shared__ float sB[TC_][N_];
    __shared__ float sC[TC_][N_];
    const int tid = threadIdx.x;
    const int b = blockIdx.x;
    const int d = (blockIdx.y << 8) + tid;

    float a2[N_], hs[N_];
#pragma unroll
    for (int n = 0; n < N_; ++n) {
        a2[n] = -__expf(A_log_l[d * N_ + n]) * 1.44269504f;
        hs[n] = 0.f;
    }
    const float Dpd = Dp_l[d];

    for (int ch = 0; ch < T_ / TC_; ++ch) {
        __syncthreads();
        for (int i = tid; i < TC_ * N_; i += 256) {
            const int tl = i >> 4, n = i & 15;
            const size_t base = ((size_t)b * T_ + (size_t)ch * TC_ + tl) * 64;
            sB[tl][n] = dbc[base + 32 + n];
            sC[tl][n] = dbc[base + 48 + n];
        }
        __syncthreads();
        for (int tt = 0; tt < TC_; ++tt) {
            const size_t m = (size_t)b * T_ + (size_t)ch * TC_ + tt;
            const float dl = xz[m * 2048 + d];
            const float uv = u[m * DI_ + d];
            const float du = dl * uv;
            float yv = 0.f;
#pragma unroll
            for (int n = 0; n < N_; ++n) {
                const float dA = exp2f(dl * a2[n]);
                hs[n] = fmaf(dA, hs[n], du * sB[tt][n]);
                yv = fmaf(hs[n], sC[tt][n], yv);
            }
            yv = fmaf(uv, Dpd, yv);
            const float zv = xz[m * 2048 + DI_ + d];
            g[m * DI_ + d] = yv * silu_f(zv);
        }
    }
}

extern "C" void kernel_launch(void* const* d_in, const int* in_sizes, int n_in,
                              void* d_out, int out_size, void* d_ws, size_t ws_size,
                              hipStream_t stream) {
    const float* x     = (const float*)d_in[0];
    const float* Wi    = (const float*)d_in[1];
    const float* bi    = (const float*)d_in[2];
    const float* Win   = (const float*)d_in[3];
    const float* convw = (const float*)d_in[4];
    const float* convb = (const float*)d_in[5];
    const float* Wx    = (const float*)d_in[6];
    const float* Wdt   = (const float*)d_in[7];
    const float* bdt   = (const float*)d_in[8];
    const float* A_log = (const float*)d_in[9];
    const float* Dp    = (const float*)d_in[10];
    const float* Wout  = (const float*)d_in[11];
    const float* Wo    = (const float*)d_in[12];
    const float* bo    = (const float*)d_in[13];
    float* out = (float*)d_out;

    // Per-row f32 units: xz 2048 + u 1024 + dbc 64 + h 512 + g 1024 +
    // Ah (Mc*1024 ushorts = 512 f32-eq) = 5184.
    // Extras: Bh 2048*512 ushorts = 524288 f32-eq + 16 f32 scale slots.
    const size_t rowf = 5184;
    const size_t wextra = 524288 + 16;
    int CB = BB_;
    while (CB > 1 && ((size_t)CB * T_ * rowf + wextra) * sizeof(float) > ws_size) CB >>= 1;
    const size_t Mc = (size_t)CB * T_;

    const dim3 blk(256);
    const int rowTiles = (int)(Mc / 128);
    const dim3 amaxg(1024);

    float* ws   = (float*)d_ws;
    float* xz   = ws;                     // Mc*2048
    float* u    = xz + Mc * 2048;         // Mc*1024
    float* dbc  = u  + Mc * 1024;         // Mc*64
    float* h    = dbc + Mc * 64;          // Mc*512
    float* g    = h  + Mc * 512;          // Mc*1024
    unsigned short* Ah = (unsigned short*)(g + Mc * 1024);   // Mc*1024 ushort
    unsigned short* Bh = Ah + Mc * 1024;                     // 1M ushort
    unsigned int* scales = (unsigned int*)(Bh + 2048 * 512); // 16 slots

    for (int c = 0; c < BB_ / CB; ++c) {
        const float* x_c = x + (size_t)c * Mc * DIN_;
        float* out_c     = out + (size_t)c * Mc * DOUT_;

        hipMemsetAsync(scales, 0, 16 * sizeof(unsigned int), stream);

        // h = x @ Wi.T + bi   (fp32, K=64 — small)
        gemm_t128<1><<<dim3(D_ / 128, rowTiles), blk, 0, stream>>>(
            x_c, DIN_, Wi, DIN_, bi, h, D_, DIN_);

        for (int l = 0; l < L_; ++l) {
            const float* Win_l  = Win  + (size_t)l * 2 * DI_ * D_;
            const float* cw_l   = convw + (size_t)l * DI_ * DC_;
            const float* cb_l   = convb + (size_t)l * DI_;
            const float* Wx_l   = Wx   + (size_t)l * (R_ + 2 * N_) * DI_;
            const float* Wdt_l  = Wdt  + (size_t)l * DI_ * R_;
            const float* bdt_l  = bdt  + (size_t)l * DI_;
            const float* Alog_l = A_log + (size_t)l * DI_ * N_;
            const float* Dp_l   = Dp   + (size_t)l * DI_;
            const float* Wout_l = Wout + (size_t)l * D_ * DI_;
            unsigned int* s_h  = scales + l * 4 + 0;
            unsigned int* s_wi = scales + l * 4 + 1;
            unsigned int* s_g  = scales + l * 4 + 2;
            unsigned int* s_wo = scales + l * 4 + 3;

            // xz = h @ Win.T  (scaled f16 MFMA)
            amax_kernel<<<amaxg, blk, 0, stream>>>(h, Mc * 128, s_h);
            amax_kernel<<<amaxg, blk, 0, stream>>>(Win_l, 262144, s_wi);
            cast_scale_kernel<<<dim3((unsigned)(Mc * 512 / 1024)), blk, 0, stream>>>(h, Ah, s_h);
            cast_scale_kernel<<<dim3(2048 * 512 / 1024), blk, 0, stream>>>(Win_l, Bh, s_wi);
            gemm_f16_t128<0><<<dim3(2048 / 128, rowTiles), blk, 0, stream>>>(
                Ah, D_, Bh, D_, nullptr, xz, 2048, D_, s_h, s_wi);

            // u = silu(causal_dwconv(xin) + cb)
            conv_silu_kernel<<<dim3((unsigned)(Mc * DI_ / 256)), blk, 0, stream>>>(
                xz, cw_l, cb_l, u);

            // dbc = u @ Wx.T  (fp32)
            gemm_t64n<<<dim3(1, rowTiles), blk, 0, stream>>>(
                u, DI_, Wx_l, DI_, dbc, 64, DI_);

            // delta = softplus(dt @ Wdt.T + bdt) into xz[:, :1024] (ldc=2048)
            gemm_t128<2><<<dim3(DI_ / 128, rowTiles), blk, 0, stream>>>(
                dbc, 64, Wdt_l, R_, bdt_l, xz, 2048, R_);

            // selective scan + epilogue -> g (fp32)
            scan_kernel<<<dim3(CB, DI_ / 256), blk, 0, stream>>>(
                u, xz, dbc, Alog_l, Dp_l, g);

            // h = g @ Wout.T  (scaled f16 MFMA)
            amax_kernel<<<amaxg, blk, 0, stream>>>(g, Mc * 256, s_g);
            amax_kernel<<<amaxg, blk, 0, stream>>>(Wout_l, 131072, s_wo);
            cast_scale_kernel<<<dim3((unsigned)(Mc * 1024 / 1024)), blk, 0, stream>>>(g, Ah, s_g);
            cast_scale_kernel<<<dim3(512 * 1024 / 1024), blk, 0, stream>>>(Wout_l, Bh, s_wo);
            gemm_f16_t128<0><<<dim3(D_ / 128, rowTiles), blk, 0, stream>>>(
                Ah, DI_, Bh, DI_, nullptr, h, D_, DI_, s_g, s_wo);
        }

        // out = tanh(h @ Wo.T + bo)  (scaled f16 MFMA)
        unsigned int* s_hf = scales + 12;
        unsigned int* s_wf = scales + 13;
        amax_kernel<<<amaxg, blk, 0, stream>>>(h, Mc * 128, s_hf);
        amax_kernel<<<amaxg, blk, 0, stream>>>(Wo, 16384, s_wf);
        cast_scale_kernel<<<dim3((unsigned)(Mc * 512 / 1024)), blk, 0, stream>>>(h, Ah, s_hf);
        cast_scale_kernel<<<dim3(128 * 512 / 1024), blk, 0, stream>>>(Wo, Bh, s_wf);
        gemm_f16_t128<3><<<dim3(DOUT_ / 128, rowTiles), blk, 0, stream>>>(
            Ah, D_, Bh, D_, bo, out_c, DOUT_, D_, s_hf, s_wf);
    }
}

// Round 8
// 3890.358 us; speedup vs baseline: 5.2988x; 5.2988x over previous
//
#include <hip/hip_runtime.h>
#include <hip/hip_bf16.h>

#define BB_ 16
#define T_ 2048
#define DIN_ 64
#define D_ 512
#define DI_ 1024
#define N_ 16
#define DC_ 4
#define R_ 32
#define L_ 3
#define DOUT_ 128
#define CL_ 128              // scan chunk length
#define NCH_ (T_ / CL_)      // 16 chunks

typedef __attribute__((ext_vector_type(8))) _Float16 f16x8;
typedef __attribute__((ext_vector_type(4))) float f32x4;

__device__ __forceinline__ float silu_f(float x) { return x / (1.f + __expf(-x)); }

__device__ __forceinline__ unsigned short f2h(float f) {
    union { _Float16 h; unsigned short u; } c;
    c.h = (_Float16)f;   // RNE
    return c.u;
}

// decode scale from amax bits: s = 2^(11 - e), so s*amax lands in [2^11, 2^12)
__device__ __forceinline__ float decode_scale(unsigned int bits) {
    if (bits == 0u) return 1.f;
    const int E = (int)(bits >> 23) & 0xFF;
    return __uint_as_float((unsigned)(265 - E) << 23);
}

// grid-stride absmax (contiguous, float4) -> atomicMax on float bits
__global__ __launch_bounds__(256) void amax_kernel(
    const float* __restrict__ in, size_t n4, unsigned int* __restrict__ slot)
{
    float m = 0.f;
    for (size_t i = (size_t)blockIdx.x * 256 + threadIdx.x; i < n4;
         i += (size_t)gridDim.x * 256) {
        const float4 v = ((const float4*)in)[i];
        m = fmaxf(m, fmaxf(fmaxf(fabsf(v.x), fabsf(v.y)),
                           fmaxf(fabsf(v.z), fabsf(v.w))));
    }
#pragma unroll
    for (int off = 32; off; off >>= 1) m = fmaxf(m, __shfl_down(m, off));
    __shared__ float sm[4];
    if ((threadIdx.x & 63) == 0) sm[threadIdx.x >> 6] = m;
    __syncthreads();
    if (threadIdx.x == 0) {
        const float b = fmaxf(fmaxf(sm[0], sm[1]), fmaxf(sm[2], sm[3]));
        atomicMax(slot, __float_as_uint(b));
    }
}

// fp32 -> f16 scaled cast over rows: element (m, col) with col < 2^shift,
// row stride ldin. Output contiguous (m << shift) + col.
__global__ __launch_bounds__(256) void cast_scale_kernel(
    const float* __restrict__ in, int ldin, int shift,
    unsigned short* __restrict__ out, const unsigned int* __restrict__ slot)
{
    const float s = decode_scale(*slot);
    const size_t gid4 = ((size_t)blockIdx.x * 256 + threadIdx.x) * 4;
    const size_t m = gid4 >> shift;
    const int col = (int)(gid4 & ((1u << shift) - 1));
    const float4 v = *(const float4*)(in + m * ldin + col);
    *(ushort4*)(out + gid4) = make_ushort4(f2h(v.x * s), f2h(v.y * s),
                                           f2h(v.z * s), f2h(v.w * s));
}

// ---------------- scaled f16 MFMA GEMM: C = (A @ B^T) * inv ----------------
// 128x128 tile, BK=32, 4 waves (2x2), per-wave 64x64 = 4x4 frags of 16x16x32.
// ACT: 0 = none, 3 = +bias then tanh. Output fp32 (+ optional amax slot).
template<int ACT>
__global__ __launch_bounds__(256) void gemm_f16_t128(
    const unsigned short* __restrict__ A, int lda,
    const unsigned short* __restrict__ B, int ldb,
    const float* __restrict__ bias,
    float* __restrict__ C, int ldc, int K,
    const unsigned int* __restrict__ sa, const unsigned int* __restrict__ sb,
    unsigned int* __restrict__ oamax)
{
    __shared__ __align__(16) unsigned short As[128 * 32];
    __shared__ __align__(16) unsigned short Bs[128 * 32];
    const int tid  = threadIdx.x;
    const int lane = tid & 63;
    const int w    = tid >> 6;
    const int wr   = (w >> 1) << 6;
    const int wc   = (w & 1) << 6;
    const int l15  = lane & 15, l4 = lane >> 4;
    const int row0 = blockIdx.y << 7, col0 = blockIdx.x << 7;
    const int tq   = tid >> 2;
    const int tr   = (tid & 3) << 3;

    const float inv = (1.f / decode_scale(*sa)) * (1.f / decode_scale(*sb));

    f32x4 acc[4][4];
#pragma unroll
    for (int m = 0; m < 4; ++m)
#pragma unroll
        for (int n = 0; n < 4; ++n) acc[m][n] = (f32x4){0.f, 0.f, 0.f, 0.f};

    for (int k0 = 0; k0 < K; k0 += 32) {
        const uint4 av0 = *(const uint4*)(A + (size_t)(row0 + tq) * lda + k0 + tr);
        const uint4 av1 = *(const uint4*)(A + (size_t)(row0 + 64 + tq) * lda + k0 + tr);
        const uint4 bv0 = *(const uint4*)(B + (size_t)(col0 + tq) * ldb + k0 + tr);
        const uint4 bv1 = *(const uint4*)(B + (size_t)(col0 + 64 + tq) * ldb + k0 + tr);
        __syncthreads();
        *(uint4*)&As[tq * 32 + tr]        = av0;
        *(uint4*)&As[(64 + tq) * 32 + tr] = av1;
        *(uint4*)&Bs[tq * 32 + tr]        = bv0;
        *(uint4*)&Bs[(64 + tq) * 32 + tr] = bv1;
        __syncthreads();

        f16x8 af[4], bfr[4];
#pragma unroll
        for (int m = 0; m < 4; ++m)
            af[m] = *(const f16x8*)&As[(wr + m * 16 + l15) * 32 + l4 * 8];
#pragma unroll
        for (int n = 0; n < 4; ++n)
            bfr[n] = *(const f16x8*)&Bs[(wc + n * 16 + l15) * 32 + l4 * 8];
#pragma unroll
        for (int m = 0; m < 4; ++m)
#pragma unroll
            for (int n = 0; n < 4; ++n)
                acc[m][n] = __builtin_amdgcn_mfma_f32_16x16x32_f16(
                    af[m], bfr[n], acc[m][n], 0, 0, 0);
    }

    float am = 0.f;
#pragma unroll
    for (int n = 0; n < 4; ++n) {
        const int col = col0 + wc + n * 16 + l15;
        float bc = 0.f;
        if (ACT == 3) bc = bias[col];
#pragma unroll
        for (int m = 0; m < 4; ++m) {
            const int rowb = row0 + wr + m * 16 + (l4 << 2);
#pragma unroll
            for (int r = 0; r < 4; ++r) {
                float v = acc[m][n][r] * inv;
                if (ACT == 3) v = tanhf(v + bc);
                C[(size_t)(rowb + r) * ldc + col] = v;
                am = fmaxf(am, fabsf(v));
            }
        }
    }
    if (oamax) {
#pragma unroll
        for (int off = 32; off; off >>= 1) am = fmaxf(am, __shfl_down(am, off));
        if (lane == 0) atomicMax(oamax, __float_as_uint(am));
    }
}

// ---------------- fp32 vector GEMM ----------------
// ACT: 0 none, 1 +bias, 2 +bias softplus.
template<int ACT>
__global__ __launch_bounds__(256) void gemm_t128(
    const float* __restrict__ A, int lda,
    const float* __restrict__ B, int ldb,
    const float* __restrict__ bias,
    float* __restrict__ C, int ldc, int K,
    unsigned int* __restrict__ oamax)
{
    __shared__ __align__(16) float As[8][128];
    __shared__ __align__(16) float Bs[8][128];
    const int tid  = threadIdx.x;
    const int row0 = blockIdx.y << 7;
    const int col0 = blockIdx.x << 7;
    const int tx = tid & 15, ty = tid >> 4;

    float acc[8][8];
#pragma unroll
    for (int i = 0; i < 8; ++i)
#pragma unroll
        for (int j = 0; j < 8; ++j) acc[i][j] = 0.f;

    const int arow = tid >> 1;
    const int acol = (tid & 1) << 2;
    const float* Ap = A + (size_t)(row0 + arow) * lda + acol;
    const float* Bp = B + (size_t)(col0 + arow) * ldb + acol;

    for (int k0 = 0; k0 < K; k0 += 8) {
        const float4 av = *(const float4*)(Ap + k0);
        const float4 bv = *(const float4*)(Bp + k0);
        __syncthreads();
        As[acol + 0][arow] = av.x; As[acol + 1][arow] = av.y;
        As[acol + 2][arow] = av.z; As[acol + 3][arow] = av.w;
        Bs[acol + 0][arow] = bv.x; Bs[acol + 1][arow] = bv.y;
        Bs[acol + 2][arow] = bv.z; Bs[acol + 3][arow] = bv.w;
        __syncthreads();
#pragma unroll
        for (int k = 0; k < 8; ++k) {
            float a[8], b[8];
            *(float4*)&a[0] = *(const float4*)&As[k][ty << 3];
            *(float4*)&a[4] = *(const float4*)&As[k][(ty << 3) + 4];
            *(float4*)&b[0] = *(const float4*)&Bs[k][tx << 3];
            *(float4*)&b[4] = *(const float4*)&Bs[k][(tx << 3) + 4];
#pragma unroll
            for (int i = 0; i < 8; ++i)
#pragma unroll
                for (int j = 0; j < 8; ++j)
                    acc[i][j] = fmaf(a[i], b[j], acc[i][j]);
        }
    }

    float bv8[8];
#pragma unroll
    for (int j = 0; j < 8; ++j) bv8[j] = (ACT >= 1) ? bias[col0 + (tx << 3) + j] : 0.f;

    float am = 0.f;
#pragma unroll
    for (int i = 0; i < 8; ++i) {
        float v[8];
#pragma unroll
        for (int j = 0; j < 8; ++j) {
            float t = (ACT >= 1) ? (acc[i][j] + bv8[j]) : acc[i][j];
            if (ACT == 2) t = (t > 20.f) ? t : log1pf(__expf(t));
            v[j] = t;
            am = fmaxf(am, fabsf(t));
        }
        float* Cp = C + (size_t)(row0 + (ty << 3) + i) * ldc + col0 + (tx << 3);
        *(float4*)(Cp)     = make_float4(v[0], v[1], v[2], v[3]);
        *(float4*)(Cp + 4) = make_float4(v[4], v[5], v[6], v[7]);
    }
    if (oamax) {
#pragma unroll
        for (int off = 32; off; off >>= 1) am = fmaxf(am, __shfl_down(am, off));
        if ((tid & 63) == 0) atomicMax(oamax, __float_as_uint(am));
    }
}

// 128x64 tile fp32 variant for N=64 (dbc GEMM)
__global__ __launch_bounds__(256) void gemm_t64n(
    const float* __restrict__ A, int lda,
    const float* __restrict__ B, int ldb,
    float* __restrict__ C, int ldc, int K)
{
    __shared__ __align__(16) float As[8][128];
    __shared__ __align__(16) float Bs[8][64];
    const int tid  = threadIdx.x;
    const int row0 = blockIdx.y << 7;
    const int col0 = blockIdx.x << 6;
    const int tx = tid & 15, ty = tid >> 4;

    float acc[8][4];
#pragma unroll
    for (int i = 0; i < 8; ++i)
#pragma unroll
        for (int j = 0; j < 4; ++j) acc[i][j] = 0.f;

    const int arow = tid >> 1, acol = (tid & 1) << 2;
    const int brow = tid >> 2, bcol = (tid & 3) << 1;
    const float* Ap = A + (size_t)(row0 + arow) * lda + acol;
    const float* Bp = B + (size_t)(col0 + brow) * ldb + bcol;

    for (int k0 = 0; k0 < K; k0 += 8) {
        const float4 av = *(const float4*)(Ap + k0);
        const float2 bv = *(const float2*)(Bp + k0);
        __syncthreads();
        As[acol + 0][arow] = av.x; As[acol + 1][arow] = av.y;
        As[acol + 2][arow] = av.z; As[acol + 3][arow] = av.w;
        Bs[bcol + 0][brow] = bv.x;
        Bs[bcol + 1][brow] = bv.y;
        __syncthreads();
#pragma unroll
        for (int k = 0; k < 8; ++k) {
            float a[8], b[4];
            *(float4*)&a[0] = *(const float4*)&As[k][ty << 3];
            *(float4*)&a[4] = *(const float4*)&As[k][(ty << 3) + 4];
            *(float4*)&b[0] = *(const float4*)&Bs[k][tx << 2];
#pragma unroll
            for (int i = 0; i < 8; ++i)
#pragma unroll
                for (int j = 0; j < 4; ++j)
                    acc[i][j] = fmaf(a[i], b[j], acc[i][j]);
        }
    }

#pragma unroll
    for (int i = 0; i < 8; ++i) {
        float* Cp = C + (size_t)(row0 + (ty << 3) + i) * ldc + col0 + (tx << 2);
        *(float4*)(Cp) = make_float4(acc[i][0], acc[i][1], acc[i][2], acc[i][3]);
    }
}

// depthwise causal conv (DC=4) + bias + SiLU. Reads xin = xz[:, :DI_].
__global__ __launch_bounds__(256) void conv_silu_kernel(
    const float* __restrict__ xz, const float* __restrict__ cw,
    const float* __restrict__ cb, float* __restrict__ u)
{
    const size_t idx = (size_t)blockIdx.x * 256 + threadIdx.x; // m*DI + c
    const int c = (int)(idx & (DI_ - 1));
    const size_t m = idx >> 10;
    const int t = (int)(m & (T_ - 1));
    const float w0 = cw[c * DC_ + 0], w1 = cw[c * DC_ + 1];
    const float w2 = cw[c * DC_ + 2], w3 = cw[c * DC_ + 3];
    const float* xr = xz + m * 2048 + c;
    float acc = cb[c];
    if (t >= 3) acc = fmaf(xr[-3 * 2048], w0, acc);
    if (t >= 2) acc = fmaf(xr[-2 * 2048], w1, acc);
    if (t >= 1) acc = fmaf(xr[-1 * 2048], w2, acc);
    acc = fmaf(xr[0], w3, acc);
    u[idx] = silu_f(acc);
}

// -------- chunk-parallel selective scan (linear recurrence, 3 phases) -----
// State per (b,d): 16 values. delta at xz[m*2048+d], z at xz[m*2048+1024+d].
// P/S layout: idx(b,ch,n,d) = (((b*NCH+ch)*N + n) << 10) + d.

__global__ __launch_bounds__(256) void scan_pass1(
    const float* __restrict__ xz, const float* __restrict__ u,
    const float* __restrict__ dbc, const float* __restrict__ A_log_l,
    float* __restrict__ P, float* __restrict__ S)
{
    __shared__ float sB[CL_][N_];
    const int tid = threadIdx.x;
    const int b = blockIdx.x, ch = blockIdx.z;
    const int d = (blockIdx.y << 8) + tid;

    float a2[N_], Pm[N_], hs[N_];
#pragma unroll
    for (int n = 0; n < N_; ++n) {
        a2[n] = -__expf(A_log_l[d * N_ + n]) * 1.44269504f;
        Pm[n] = 1.f; hs[n] = 0.f;
    }
    for (int i = tid; i < CL_ * N_; i += 256) {
        const int tl = i >> 4, n = i & 15;
        sB[tl][n] = dbc[((size_t)b * T_ + ch * CL_ + tl) * 64 + 32 + n];
    }
    __syncthreads();

    for (int tt = 0; tt < CL_; ++tt) {
        const size_t m = (size_t)b * T_ + ch * CL_ + tt;
        const float dl = xz[m * 2048 + d];
        const float du = dl * u[m * DI_ + d];
#pragma unroll
        for (int n = 0; n < N_; ++n) {
            const float dA = exp2f(dl * a2[n]);
            Pm[n] *= dA;
            hs[n] = fmaf(dA, hs[n], du * sB[tt][n]);
        }
    }
#pragma unroll
    for (int n = 0; n < N_; ++n) {
        const size_t idx = (size_t)(((b * NCH_ + ch) * N_ + n) << 10) + d;
        P[idx] = Pm[n]; S[idx] = hs[n];
    }
}

// carry: per (b,n,d) combine chunks sequentially; S[ch] becomes h_init(ch).
__global__ __launch_bounds__(256) void scan_carry(
    const float* __restrict__ P, float* __restrict__ S)
{
    const size_t gid = (size_t)blockIdx.x * 256 + threadIdx.x;
    const int d = (int)(gid & 1023);
    const int n = (int)((gid >> 10) & 15);
    const int b = (int)(gid >> 14);
    float hc = 0.f;
    for (int ch = 0; ch < NCH_; ++ch) {
        const size_t idx = (size_t)(((b * NCH_ + ch) * N_ + n) << 10) + d;
        const float p = P[idx], s = S[idx];
        S[idx] = hc;
        hc = fmaf(p, hc, s);
    }
}

// pass3: redo in-chunk scan from h_init, emit g = (y + u*Dp)*silu(z) over
// the delta slot; track amax(g) -> slot.
__global__ __launch_bounds__(256) void scan_pass3(
    float* __restrict__ xz, const float* __restrict__ u,
    const float* __restrict__ dbc, const float* __restrict__ A_log_l,
    const float* __restrict__ Dp_l, const float* __restrict__ S,
    unsigned int* __restrict__ gmax)
{
    __shared__ float sB[CL_][N_];
    __shared__ float sC[CL_][N_];
    const int tid = threadIdx.x;
    const int b = blockIdx.x, ch = blockIdx.z;
    const int d = (blockIdx.y << 8) + tid;

    float a2[N_], hs[N_];
#pragma unroll
    for (int n = 0; n < N_; ++n) {
        a2[n] = -__expf(A_log_l[d * N_ + n]) * 1.44269504f;
        hs[n] = S[(size_t)(((b * NCH_ + ch) * N_ + n) << 10) + d];
    }
    const float Dpd = Dp_l[d];
    for (int i = tid; i < CL_ * N_; i += 256) {
        const int tl = i >> 4, n = i & 15;
        const size_t base = ((size_t)b * T_ + ch * CL_ + tl) * 64;
        sB[tl][n] = dbc[base + 32 + n];
        sC[tl][n] = dbc[base + 48 + n];
    }
    __syncthreads();

    float gm = 0.f;
    for (int tt = 0; tt < CL_; ++tt) {
        const size_t m = (size_t)b * T_ + ch * CL_ + tt;
        const float dl = xz[m * 2048 + d];
        const float uv = u[m * DI_ + d];
        const float du = dl * uv;
        float yv = 0.f;
#pragma unroll
        for (int n = 0; n < N_; ++n) {
            const float dA = exp2f(dl * a2[n]);
            hs[n] = fmaf(dA, hs[n], du * sB[tt][n]);
            yv = fmaf(hs[n], sC[tt][n], yv);
        }
        yv = fmaf(uv, Dpd, yv);
        const float g = yv * silu_f(xz[m * 2048 + DI_ + d]);
        xz[m * 2048 + d] = g;
        gm = fmaxf(gm, fabsf(g));
    }
#pragma unroll
    for (int off = 32; off; off >>= 1) gm = fmaxf(gm, __shfl_down(gm, off));
    if ((tid & 63) == 0) atomicMax(gmax, __float_as_uint(gm));
}

extern "C" void kernel_launch(void* const* d_in, const int* in_sizes, int n_in,
                              void* d_out, int out_size, void* d_ws, size_t ws_size,
                              hipStream_t stream) {
    const float* x     = (const float*)d_in[0];
    const float* Wi    = (const float*)d_in[1];
    const float* bi    = (const float*)d_in[2];
    const float* Win   = (const float*)d_in[3];
    const float* convw = (const float*)d_in[4];
    const float* convb = (const float*)d_in[5];
    const float* Wx    = (const float*)d_in[6];
    const float* Wdt   = (const float*)d_in[7];
    const float* bdt   = (const float*)d_in[8];
    const float* A_log = (const float*)d_in[9];
    const float* Dp    = (const float*)d_in[10];
    const float* Wout  = (const float*)d_in[11];
    const float* Wo    = (const float*)d_in[12];
    const float* bo    = (const float*)d_in[13];
    float* out = (float*)d_out;

    // Per-row f32: xz 2048 + u 1024 + dbc 64 + AhF 512 (Ah f16 / scan P,S) = 3648.
    // Extras: f16 weights (3 Win + 3 Wout + Wo) + 16 scale slots.
    const size_t rowf = 3648;
    const size_t wextra = (3 * 1048576 + 3 * 524288 + 65536) / 2 + 16;
    int CB = BB_;
    while (CB > 1 && ((size_t)CB * T_ * rowf + wextra) * sizeof(float) > ws_size) CB >>= 1;
    const size_t Mc = (size_t)CB * T_;

    const dim3 blk(256);
    const int rowTiles = (int)(Mc / 128);

    float* ws   = (float*)d_ws;
    float* xz   = ws;                    // Mc*2048 (xin/delta/g | z+h)
    float* u    = xz + Mc * 2048;        // Mc*1024
    float* dbc  = u  + Mc * 1024;        // Mc*64
    float* AhF  = dbc + Mc * 64;         // Mc*512 f32 (= Mc*1024 ushorts)
    unsigned short* Ah = (unsigned short*)AhF;
    float* Pbuf = AhF;                               // CB*NCH*N*DI floats
    float* Sbuf = AhF + (size_t)CB * NCH_ * N_ * DI_;
    unsigned short* WinH  = (unsigned short*)(AhF + Mc * 512);
    unsigned short* WoutH = WinH + 3 * 1048576;
    unsigned short* WoH   = WoutH + 3 * 524288;
    unsigned int* scales  = (unsigned int*)(WoH + 65536);
    // slots: 0-2 Win[l], 3-5 Wout[l], 6 Wo, 8+l h[l] (l=0..3), 12+l g[l]

    hipMemsetAsync(scales, 0, 16 * sizeof(unsigned int), stream);

    // ---- weight amax + f16 casts (once per launch) ----
    for (int l = 0; l < L_; ++l) {
        const float* Win_l  = Win  + (size_t)l * 2 * DI_ * D_;
        const float* Wout_l = Wout + (size_t)l * D_ * DI_;
        amax_kernel<<<dim3(1024), blk, 0, stream>>>(Win_l, 262144, scales + l);
        amax_kernel<<<dim3(512), blk, 0, stream>>>(Wout_l, 131072, scales + 3 + l);
        cast_scale_kernel<<<dim3(1024), blk, 0, stream>>>(
            Win_l, 1 << 20, 20, WinH + (size_t)l * 1048576, scales + l);
        cast_scale_kernel<<<dim3(512), blk, 0, stream>>>(
            Wout_l, 1 << 19, 19, WoutH + (size_t)l * 524288, scales + 3 + l);
    }
    amax_kernel<<<dim3(64), blk, 0, stream>>>(Wo, 16384, scales + 6);
    cast_scale_kernel<<<dim3(64), blk, 0, stream>>>(Wo, 1 << 16, 16, WoH, scales + 6);

    for (int c = 0; c < BB_ / CB; ++c) {
        const float* x_c = x + (size_t)c * Mc * DIN_;
        float* out_c     = out + (size_t)c * Mc * DOUT_;
        float* hbuf      = xz + 1024;    // h lives in dead z-half, ld 2048

        hipMemsetAsync(scales + 8, 0, 8 * sizeof(unsigned int), stream);

        // h = x @ Wi.T + bi  (fp32, K=64) -> xz[:,1024:1536], amax -> s_h[0]
        gemm_t128<1><<<dim3(D_ / 128, rowTiles), blk, 0, stream>>>(
            x_c, DIN_, Wi, DIN_, bi, hbuf, 2048, DIN_, scales + 8);

        for (int l = 0; l < L_; ++l) {
            const float* cw_l   = convw + (size_t)l * DI_ * DC_;
            const float* cb_l   = convb + (size_t)l * DI_;
            const float* Wx_l   = Wx   + (size_t)l * (R_ + 2 * N_) * DI_;
            const float* Wdt_l  = Wdt  + (size_t)l * DI_ * R_;
            const float* bdt_l  = bdt  + (size_t)l * DI_;
            const float* Alog_l = A_log + (size_t)l * DI_ * N_;
            const float* Dp_l   = Dp   + (size_t)l * DI_;

            // Ah = f16(h)  (strided: width 512, ld 2048)
            cast_scale_kernel<<<dim3((unsigned)(Mc * 512 / 1024)), blk, 0, stream>>>(
                hbuf, 2048, 9, Ah, scales + 8 + l);

            // xz = h @ Win.T  (f16 MFMA) — overwrites whole xz incl. h slot
            gemm_f16_t128<0><<<dim3(2048 / 128, rowTiles), blk, 0, stream>>>(
                Ah, D_, WinH + (size_t)l * 1048576, D_, nullptr,
                xz, 2048, D_, scales + 8 + l, scales + l, nullptr);

            // u = silu(causal_dwconv(xin) + cb)
            conv_silu_kernel<<<dim3((unsigned)(Mc * DI_ / 256)), blk, 0, stream>>>(
                xz, cw_l, cb_l, u);

            // dbc = u @ Wx.T  (fp32)
            gemm_t64n<<<dim3(1, rowTiles), blk, 0, stream>>>(
                u, DI_, Wx_l, DI_, dbc, 64, DI_);

            // delta = softplus(dt @ Wdt.T + bdt) -> xz[:, :1024] (ldc 2048)
            gemm_t128<2><<<dim3(DI_ / 128, rowTiles), blk, 0, stream>>>(
                dbc, 64, Wdt_l, R_, bdt_l, xz, 2048, R_, nullptr);

            // chunk-parallel scan; g -> xz[:, :1024], amax -> s_g[l]
            scan_pass1<<<dim3(CB, DI_ / 256, NCH_), blk, 0, stream>>>(
                xz, u, dbc, Alog_l, Pbuf, Sbuf);
            scan_carry<<<dim3(CB * 64), blk, 0, stream>>>(Pbuf, Sbuf);
            scan_pass3<<<dim3(CB, DI_ / 256, NCH_), blk, 0, stream>>>(
                xz, u, dbc, Alog_l, Dp_l, Sbuf, scales + 12 + l);

            // Ah = f16(g)  (strided: width 1024, ld 2048)
            cast_scale_kernel<<<dim3((unsigned)(Mc * 1024 / 1024)), blk, 0, stream>>>(
                xz, 2048, 10, Ah, scales + 12 + l);

            // h = g @ Wout.T  (f16 MFMA) -> xz[:,1024:1536], amax -> s_h[l+1]
            gemm_f16_t128<0><<<dim3(D_ / 128, rowTiles), blk, 0, stream>>>(
                Ah, DI_, WoutH + (size_t)l * 524288, DI_, nullptr,
                hbuf, 2048, DI_, scales + 12 + l, scales + 3 + l, scales + 9 + l);
        }

        // out = tanh(h @ Wo.T + bo)
        cast_scale_kernel<<<dim3((unsigned)(Mc * 512 / 1024)), blk, 0, stream>>>(
            hbuf, 2048, 9, Ah, scales + 11);
        gemm_f16_t128<3><<<dim3(DOUT_ / 128, rowTiles), blk, 0, stream>>>(
            Ah, D_, WoH, D_, bo, out_c, DOUT_, D_, scales + 11, scales + 6, nullptr);
    }
}

// Round 9
// 3579.351 us; speedup vs baseline: 5.7592x; 1.0869x over previous
//
#include <hip/hip_runtime.h>
#include <hip/hip_bf16.h>

#define BB_ 16
#define T_ 2048
#define DIN_ 64
#define D_ 512
#define DI_ 1024
#define N_ 16
#define DC_ 4
#define R_ 32
#define L_ 3
#define DOUT_ 128
#define CL_ 128              // scan chunk length
#define NCH_ (T_ / CL_)      // 16 chunks

typedef __attribute__((ext_vector_type(8))) _Float16 f16x8;
typedef __attribute__((ext_vector_type(4))) float f32x4;

__device__ __forceinline__ float silu_f(float x) { return x / (1.f + __expf(-x)); }

__device__ __forceinline__ unsigned short f2h(float f) {
    union { _Float16 h; unsigned short u; } c;
    c.h = (_Float16)f;   // RNE
    return c.u;
}

// decode scale from amax bits: s = 2^(11 - e), so s*amax lands in [2^11, 2^12)
__device__ __forceinline__ float decode_scale(unsigned int bits) {
    if (bits == 0u) return 1.f;
    const int E = (int)(bits >> 23) & 0xFF;
    return __uint_as_float((unsigned)(265 - E) << 23);
}

// grid-stride absmax (contiguous, float4) -> atomicMax on float bits
__global__ __launch_bounds__(256) void amax_kernel(
    const float* __restrict__ in, size_t n4, unsigned int* __restrict__ slot)
{
    float m = 0.f;
    for (size_t i = (size_t)blockIdx.x * 256 + threadIdx.x; i < n4;
         i += (size_t)gridDim.x * 256) {
        const float4 v = ((const float4*)in)[i];
        m = fmaxf(m, fmaxf(fmaxf(fabsf(v.x), fabsf(v.y)),
                           fmaxf(fabsf(v.z), fabsf(v.w))));
    }
#pragma unroll
    for (int off = 32; off; off >>= 1) m = fmaxf(m, __shfl_down(m, off));
    __shared__ float sm[4];
    if ((threadIdx.x & 63) == 0) sm[threadIdx.x >> 6] = m;
    __syncthreads();
    if (threadIdx.x == 0) {
        const float b = fmaxf(fmaxf(sm[0], sm[1]), fmaxf(sm[2], sm[3]));
        atomicMax(slot, __float_as_uint(b));
    }
}

// fp32 -> f16 scaled cast over rows: element (m, col) with col < 2^shift,
// row stride ldin. Output contiguous (m << shift) + col.
__global__ __launch_bounds__(256) void cast_scale_kernel(
    const float* __restrict__ in, int ldin, int shift,
    unsigned short* __restrict__ out, const unsigned int* __restrict__ slot)
{
    const float s = decode_scale(*slot);
    const size_t gid4 = ((size_t)blockIdx.x * 256 + threadIdx.x) * 4;
    const size_t m = gid4 >> shift;
    const int col = (int)(gid4 & ((1u << shift) - 1));
    const float4 v = *(const float4*)(in + m * ldin + col);
    *(ushort4*)(out + gid4) = make_ushort4(f2h(v.x * s), f2h(v.y * s),
                                           f2h(v.z * s), f2h(v.w * s));
}

// ---------------- scaled f16 MFMA GEMM: C = (A @ B^T) * inv ----------------
// 128x128 tile, BK=32, 4 waves (2x2), per-wave 64x64 = 4x4 frags of 16x16x32.
// Software-pipelined: global loads for step k+1 issued before MFMA of step k.
// ACT: 0 = none, 3 = +bias then tanh. Output fp32 (+ optional amax slot).
template<int ACT>
__global__ __launch_bounds__(256) void gemm_f16_t128(
    const unsigned short* __restrict__ A, int lda,
    const unsigned short* __restrict__ B, int ldb,
    const float* __restrict__ bias,
    float* __restrict__ C, int ldc, int K,
    const unsigned int* __restrict__ sa, const unsigned int* __restrict__ sb,
    unsigned int* __restrict__ oamax)
{
    __shared__ __align__(16) unsigned short As[128 * 32];
    __shared__ __align__(16) unsigned short Bs[128 * 32];
    const int tid  = threadIdx.x;
    const int lane = tid & 63;
    const int w    = tid >> 6;
    const int wr   = (w >> 1) << 6;
    const int wc   = (w & 1) << 6;
    const int l15  = lane & 15, l4 = lane >> 4;
    const int row0 = blockIdx.y << 7, col0 = blockIdx.x << 7;
    const int tq   = tid >> 2;
    const int tr   = (tid & 3) << 3;

    const float inv = (1.f / decode_scale(*sa)) * (1.f / decode_scale(*sb));

    const unsigned short* Ar0 = A + (size_t)(row0 + tq) * lda + tr;
    const unsigned short* Ar1 = A + (size_t)(row0 + 64 + tq) * lda + tr;
    const unsigned short* Br0 = B + (size_t)(col0 + tq) * ldb + tr;
    const unsigned short* Br1 = B + (size_t)(col0 + 64 + tq) * ldb + tr;

    f32x4 acc[4][4];
#pragma unroll
    for (int m = 0; m < 4; ++m)
#pragma unroll
        for (int n = 0; n < 4; ++n) acc[m][n] = (f32x4){0.f, 0.f, 0.f, 0.f};

    uint4 av0 = *(const uint4*)(Ar0);
    uint4 av1 = *(const uint4*)(Ar1);
    uint4 bv0 = *(const uint4*)(Br0);
    uint4 bv1 = *(const uint4*)(Br1);

    for (int k0 = 0; k0 < K; k0 += 32) {
        __syncthreads();
        *(uint4*)&As[tq * 32 + tr]        = av0;
        *(uint4*)&As[(64 + tq) * 32 + tr] = av1;
        *(uint4*)&Bs[tq * 32 + tr]        = bv0;
        *(uint4*)&Bs[(64 + tq) * 32 + tr] = bv1;
        __syncthreads();

        if (k0 + 32 < K) {   // issue next-step loads; waited at next ds_write
            av0 = *(const uint4*)(Ar0 + k0 + 32);
            av1 = *(const uint4*)(Ar1 + k0 + 32);
            bv0 = *(const uint4*)(Br0 + k0 + 32);
            bv1 = *(const uint4*)(Br1 + k0 + 32);
        }

        f16x8 af[4], bfr[4];
#pragma unroll
        for (int m = 0; m < 4; ++m)
            af[m] = *(const f16x8*)&As[(wr + m * 16 + l15) * 32 + l4 * 8];
#pragma unroll
        for (int n = 0; n < 4; ++n)
            bfr[n] = *(const f16x8*)&Bs[(wc + n * 16 + l15) * 32 + l4 * 8];
#pragma unroll
        for (int m = 0; m < 4; ++m)
#pragma unroll
            for (int n = 0; n < 4; ++n)
                acc[m][n] = __builtin_amdgcn_mfma_f32_16x16x32_f16(
                    af[m], bfr[n], acc[m][n], 0, 0, 0);
    }

    float am = 0.f;
#pragma unroll
    for (int n = 0; n < 4; ++n) {
        const int col = col0 + wc + n * 16 + l15;
        float bc = 0.f;
        if (ACT == 3) bc = bias[col];
#pragma unroll
        for (int m = 0; m < 4; ++m) {
            const int rowb = row0 + wr + m * 16 + (l4 << 2);
#pragma unroll
            for (int r = 0; r < 4; ++r) {
                float v = acc[m][n][r] * inv;
                if (ACT == 3) v = tanhf(v + bc);
                C[(size_t)(rowb + r) * ldc + col] = v;
                am = fmaxf(am, fabsf(v));
            }
        }
    }
    if (oamax) {
#pragma unroll
        for (int off = 32; off; off >>= 1) am = fmaxf(am, __shfl_down(am, off));
        if (lane == 0) atomicMax(oamax, __float_as_uint(am));
    }
}

// ---- scaled f16 MFMA GEMM, 128x64 tile (dbc): C fp32 = (A @ B^T) * inv ----
// 4 waves, wave w owns rows w*32 (2x16) x 64 cols (4x16). Pipelined like t128.
__global__ __launch_bounds__(256) void gemm_f16_t64n(
    const unsigned short* __restrict__ A, int lda,
    const unsigned short* __restrict__ B, int ldb,
    float* __restrict__ C, int ldc, int K,
    const unsigned int* __restrict__ sa, const unsigned int* __restrict__ sb)
{
    __shared__ __align__(16) unsigned short As[128 * 32];
    __shared__ __align__(16) unsigned short Bs[64 * 32];
    const int tid  = threadIdx.x;
    const int lane = tid & 63;
    const int w    = tid >> 6;
    const int l15  = lane & 15, l4 = lane >> 4;
    const int row0 = blockIdx.y << 7;
    const int tq   = tid >> 2;
    const int tr   = (tid & 3) << 3;

    const float inv = (1.f / decode_scale(*sa)) * (1.f / decode_scale(*sb));

    const unsigned short* Ar0 = A + (size_t)(row0 + tq) * lda + tr;
    const unsigned short* Ar1 = A + (size_t)(row0 + 64 + tq) * lda + tr;
    const unsigned short* Br  = B + (size_t)tq * ldb + tr;   // 64 rows

    f32x4 acc[2][4];
#pragma unroll
    for (int m = 0; m < 2; ++m)
#pragma unroll
        for (int n = 0; n < 4; ++n) acc[m][n] = (f32x4){0.f, 0.f, 0.f, 0.f};

    uint4 av0 = *(const uint4*)(Ar0);
    uint4 av1 = *(const uint4*)(Ar1);
    uint4 bv  = *(const uint4*)(Br);

    for (int k0 = 0; k0 < K; k0 += 32) {
        __syncthreads();
        *(uint4*)&As[tq * 32 + tr]        = av0;
        *(uint4*)&As[(64 + tq) * 32 + tr] = av1;
        *(uint4*)&Bs[tq * 32 + tr]        = bv;
        __syncthreads();

        if (k0 + 32 < K) {
            av0 = *(const uint4*)(Ar0 + k0 + 32);
            av1 = *(const uint4*)(Ar1 + k0 + 32);
            bv  = *(const uint4*)(Br  + k0 + 32);
        }

        f16x8 af[2], bfr[4];
#pragma unroll
        for (int m = 0; m < 2; ++m)
            af[m] = *(const f16x8*)&As[(w * 32 + m * 16 + l15) * 32 + l4 * 8];
#pragma unroll
        for (int n = 0; n < 4; ++n)
            bfr[n] = *(const f16x8*)&Bs[(n * 16 + l15) * 32 + l4 * 8];
#pragma unroll
        for (int m = 0; m < 2; ++m)
#pragma unroll
            for (int n = 0; n < 4; ++n)
                acc[m][n] = __builtin_amdgcn_mfma_f32_16x16x32_f16(
                    af[m], bfr[n], acc[m][n], 0, 0, 0);
    }

#pragma unroll
    for (int n = 0; n < 4; ++n) {
        const int col = n * 16 + l15;
#pragma unroll
        for (int m = 0; m < 2; ++m) {
            const int rowb = row0 + w * 32 + m * 16 + (l4 << 2);
#pragma unroll
            for (int r = 0; r < 4; ++r)
                C[(size_t)(rowb + r) * ldc + col] = acc[m][n][r] * inv;
        }
    }
}

// ---------------- fp32 vector GEMM (small-K shapes) ----------------
// ACT: 0 none, 1 +bias, 2 +bias softplus.
template<int ACT>
__global__ __launch_bounds__(256) void gemm_t128(
    const float* __restrict__ A, int lda,
    const float* __restrict__ B, int ldb,
    const float* __restrict__ bias,
    float* __restrict__ C, int ldc, int K,
    unsigned int* __restrict__ oamax)
{
    __shared__ __align__(16) float As[8][128];
    __shared__ __align__(16) float Bs[8][128];
    const int tid  = threadIdx.x;
    const int row0 = blockIdx.y << 7;
    const int col0 = blockIdx.x << 7;
    const int tx = tid & 15, ty = tid >> 4;

    float acc[8][8];
#pragma unroll
    for (int i = 0; i < 8; ++i)
#pragma unroll
        for (int j = 0; j < 8; ++j) acc[i][j] = 0.f;

    const int arow = tid >> 1;
    const int acol = (tid & 1) << 2;
    const float* Ap = A + (size_t)(row0 + arow) * lda + acol;
    const float* Bp = B + (size_t)(col0 + arow) * ldb + acol;

    for (int k0 = 0; k0 < K; k0 += 8) {
        const float4 av = *(const float4*)(Ap + k0);
        const float4 bv = *(const float4*)(Bp + k0);
        __syncthreads();
        As[acol + 0][arow] = av.x; As[acol + 1][arow] = av.y;
        As[acol + 2][arow] = av.z; As[acol + 3][arow] = av.w;
        Bs[acol + 0][arow] = bv.x; Bs[acol + 1][arow] = bv.y;
        Bs[acol + 2][arow] = bv.z; Bs[acol + 3][arow] = bv.w;
        __syncthreads();
#pragma unroll
        for (int k = 0; k < 8; ++k) {
            float a[8], b[8];
            *(float4*)&a[0] = *(const float4*)&As[k][ty << 3];
            *(float4*)&a[4] = *(const float4*)&As[k][(ty << 3) + 4];
            *(float4*)&b[0] = *(const float4*)&Bs[k][tx << 3];
            *(float4*)&b[4] = *(const float4*)&Bs[k][(tx << 3) + 4];
#pragma unroll
            for (int i = 0; i < 8; ++i)
#pragma unroll
                for (int j = 0; j < 8; ++j)
                    acc[i][j] = fmaf(a[i], b[j], acc[i][j]);
        }
    }

    float bv8[8];
#pragma unroll
    for (int j = 0; j < 8; ++j) bv8[j] = (ACT >= 1) ? bias[col0 + (tx << 3) + j] : 0.f;

    float am = 0.f;
#pragma unroll
    for (int i = 0; i < 8; ++i) {
        float v[8];
#pragma unroll
        for (int j = 0; j < 8; ++j) {
            float t = (ACT >= 1) ? (acc[i][j] + bv8[j]) : acc[i][j];
            if (ACT == 2) t = (t > 20.f) ? t : log1pf(__expf(t));
            v[j] = t;
            am = fmaxf(am, fabsf(t));
        }
        float* Cp = C + (size_t)(row0 + (ty << 3) + i) * ldc + col0 + (tx << 3);
        *(float4*)(Cp)     = make_float4(v[0], v[1], v[2], v[3]);
        *(float4*)(Cp + 4) = make_float4(v[4], v[5], v[6], v[7]);
    }
    if (oamax) {
#pragma unroll
        for (int off = 32; off; off >>= 1) am = fmaxf(am, __shfl_down(am, off));
        if ((tid & 63) == 0) atomicMax(oamax, __float_as_uint(am));
    }
}

// depthwise causal conv (DC=4) + bias + SiLU. Reads xin = xz[:, :DI_].
__global__ __launch_bounds__(256) void conv_silu_kernel(
    const float* __restrict__ xz, const float* __restrict__ cw,
    const float* __restrict__ cb, float* __restrict__ u)
{
    const size_t idx = (size_t)blockIdx.x * 256 + threadIdx.x; // m*DI + c
    const int c = (int)(idx & (DI_ - 1));
    const size_t m = idx >> 10;
    const int t = (int)(m & (T_ - 1));
    const float w0 = cw[c * DC_ + 0], w1 = cw[c * DC_ + 1];
    const float w2 = cw[c * DC_ + 2], w3 = cw[c * DC_ + 3];
    const float* xr = xz + m * 2048 + c;
    float acc = cb[c];
    if (t >= 3) acc = fmaf(xr[-3 * 2048], w0, acc);
    if (t >= 2) acc = fmaf(xr[-2 * 2048], w1, acc);
    if (t >= 1) acc = fmaf(xr[-1 * 2048], w2, acc);
    acc = fmaf(xr[0], w3, acc);
    u[idx] = silu_f(acc);
}

// -------- chunk-parallel selective scan (linear recurrence, 3 phases) -----
// State per (b,d): 16 values. delta at xz[m*2048+d], z at xz[m*2048+1024+d].
// P/S layout: idx(b,ch,n,d) = (((b*NCH+ch)*N + n) << 10) + d.

__global__ __launch_bounds__(256) void scan_pass1(
    const float* __restrict__ xz, const float* __restrict__ u,
    const float* __restrict__ dbc, const float* __restrict__ A_log_l,
    float* __restrict__ P, float* __restrict__ S)
{
    __shared__ float sB[CL_][N_];
    const int tid = threadIdx.x;
    const int b = blockIdx.x, ch = blockIdx.z;
    const int d = (blockIdx.y << 8) + tid;

    float a2[N_], Pm[N_], hs[N_];
#pragma unroll
    for (int n = 0; n < N_; ++n) {
        a2[n] = -__expf(A_log_l[d * N_ + n]) * 1.44269504f;
        Pm[n] = 1.f; hs[n] = 0.f;
    }
    for (int i = tid; i < CL_ * N_; i += 256) {
        const int tl = i >> 4, n = i & 15;
        sB[tl][n] = dbc[((size_t)b * T_ + ch * CL_ + tl) * 64 + 32 + n];
    }
    __syncthreads();

    for (int tt = 0; tt < CL_; ++tt) {
        const size_t m = (size_t)b * T_ + ch * CL_ + tt;
        const float dl = xz[m * 2048 + d];
        const float du = dl * u[m * DI_ + d];
#pragma unroll
        for (int n = 0; n < N_; ++n) {
            const float dA = exp2f(dl * a2[n]);
            Pm[n] *= dA;
            hs[n] = fmaf(dA, hs[n], du * sB[tt][n]);
        }
    }
#pragma unroll
    for (int n = 0; n < N_; ++n) {
        const size_t idx = (size_t)(((b * NCH_ + ch) * N_ + n) << 10) + d;
        P[idx] = Pm[n]; S[idx] = hs[n];
    }
}

// carry: per (b,n,d) combine chunks sequentially; S[ch] becomes h_init(ch).
__global__ __launch_bounds__(256) void scan_carry(
    const float* __restrict__ P, float* __restrict__ S)
{
    const size_t gid = (size_t)blockIdx.x * 256 + threadIdx.x;
    const int d = (int)(gid & 1023);
    const int n = (int)((gid >> 10) & 15);
    const int b = (int)(gid >> 14);
    float hc = 0.f;
    for (int ch = 0; ch < NCH_; ++ch) {
        const size_t idx = (size_t)(((b * NCH_ + ch) * N_ + n) << 10) + d;
        const float p = P[idx], s = S[idx];
        S[idx] = hc;
        hc = fmaf(p, hc, s);
    }
}

// pass3: redo in-chunk scan from h_init, emit g = (y + u*Dp)*silu(z) over
// the delta slot; track amax(g) -> slot.
__global__ __launch_bounds__(256) void scan_pass3(
    float* __restrict__ xz, const float* __restrict__ u,
    const float* __restrict__ dbc, const float* __restrict__ A_log_l,
    const float* __restrict__ Dp_l, const float* __restrict__ S,
    unsigned int* __restrict__ gmax)
{
    __shared__ float sB[CL_][N_];
    __shared__ float sC[CL_][N_];
    const int tid = threadIdx.x;
    const int b = blockIdx.x, ch = blockIdx.z;
    const int d = (blockIdx.y << 8) + tid;

    float a2[N_], hs[N_];
#pragma unroll
    for (int n = 0; n < N_; ++n) {
        a2[n] = -__expf(A_log_l[d * N_ + n]) * 1.44269504f;
        hs[n] = S[(size_t)(((b * NCH_ + ch) * N_ + n) << 10) + d];
    }
    const float Dpd = Dp_l[d];
    for (int i = tid; i < CL_ * N_; i += 256) {
        const int tl = i >> 4, n = i & 15;
        const size_t base = ((size_t)b * T_ + ch * CL_ + tl) * 64;
        sB[tl][n] = dbc[base + 32 + n];
        sC[tl][n] = dbc[base + 48 + n];
    }
    __syncthreads();

    float gm = 0.f;
    for (int tt = 0; tt < CL_; ++tt) {
        const size_t m = (size_t)b * T_ + ch * CL_ + tt;
        const float dl = xz[m * 2048 + d];
        const float uv = u[m * DI_ + d];
        const float du = dl * uv;
        float yv = 0.f;
#pragma unroll
        for (int n = 0; n < N_; ++n) {
            const float dA = exp2f(dl * a2[n]);
            hs[n] = fmaf(dA, hs[n], du * sB[tt][n]);
            yv = fmaf(hs[n], sC[tt][n], yv);
        }
        yv = fmaf(uv, Dpd, yv);
        const float g = yv * silu_f(xz[m * 2048 + DI_ + d]);
        xz[m * 2048 + d] = g;
        gm = fmaxf(gm, fabsf(g));
    }
#pragma unroll
    for (int off = 32; off; off >>= 1) gm = fmaxf(gm, __shfl_down(gm, off));
    if ((tid & 63) == 0) atomicMax(gmax, __float_as_uint(gm));
}

extern "C" void kernel_launch(void* const* d_in, const int* in_sizes, int n_in,
                              void* d_out, int out_size, void* d_ws, size_t ws_size,
                              hipStream_t stream) {
    const float* x     = (const float*)d_in[0];
    const float* Wi    = (const float*)d_in[1];
    const float* bi    = (const float*)d_in[2];
    const float* Win   = (const float*)d_in[3];
    const float* convw = (const float*)d_in[4];
    const float* convb = (const float*)d_in[5];
    const float* Wx    = (const float*)d_in[6];
    const float* Wdt   = (const float*)d_in[7];
    const float* bdt   = (const float*)d_in[8];
    const float* A_log = (const float*)d_in[9];
    const float* Dp    = (const float*)d_in[10];
    const float* Wout  = (const float*)d_in[11];
    const float* Wo    = (const float*)d_in[12];
    const float* bo    = (const float*)d_in[13];
    float* out = (float*)d_out;

    // Per-row f32: xz 2048 + u 1024 + dbc 64 + AhF 512 (Ah f16 / scan P,S) = 3648.
    // Extras: f16 weights (3 Win + 3 Wout + Wo + 3 Wx) + 32 scale slots.
    const size_t rowf = 3648;
    const size_t wextra = (3 * 1048576 + 3 * 524288 + 65536 + 3 * 65536) / 2 + 32;
    int CB = BB_;
    while (CB > 1 && ((size_t)CB * T_ * rowf + wextra) * sizeof(float) > ws_size) CB >>= 1;
    const size_t Mc = (size_t)CB * T_;

    const dim3 blk(256);
    const int rowTiles = (int)(Mc / 128);

    float* ws   = (float*)d_ws;
    float* xz   = ws;                    // Mc*2048 (xin/delta/g | z+h)
    float* u    = xz + Mc * 2048;        // Mc*1024
    float* dbc  = u  + Mc * 1024;        // Mc*64
    float* AhF  = dbc + Mc * 64;         // Mc*512 f32 (= Mc*1024 ushorts)
    unsigned short* Ah = (unsigned short*)AhF;
    float* Pbuf = AhF;                               // CB*NCH*N*DI floats
    float* Sbuf = AhF + (size_t)CB * NCH_ * N_ * DI_;
    unsigned short* WinH  = (unsigned short*)(AhF + Mc * 512);
    unsigned short* WoutH = WinH + 3 * 1048576;
    unsigned short* WoH   = WoutH + 3 * 524288;
    unsigned short* WxH   = WoH + 65536;
    unsigned int* scales  = (unsigned int*)(WxH + 3 * 65536);
    // slots: 0-2 Win[l], 3-5 Wout[l], 6 Wo, 7-9 Wx[l],
    //        10..13 h[0..3], 14..16 g[l], 17..19 u[l]

    hipMemsetAsync(scales, 0, 32 * sizeof(unsigned int), stream);

    // ---- weight amax + f16 casts (once per launch) ----
    for (int l = 0; l < L_; ++l) {
        const float* Win_l  = Win  + (size_t)l * 2 * DI_ * D_;
        const float* Wout_l = Wout + (size_t)l * D_ * DI_;
        const float* Wx_l   = Wx   + (size_t)l * (R_ + 2 * N_) * DI_;
        amax_kernel<<<dim3(1024), blk, 0, stream>>>(Win_l, 262144, scales + l);
        amax_kernel<<<dim3(512), blk, 0, stream>>>(Wout_l, 131072, scales + 3 + l);
        amax_kernel<<<dim3(64), blk, 0, stream>>>(Wx_l, 16384, scales + 7 + l);
        cast_scale_kernel<<<dim3(1024), blk, 0, stream>>>(
            Win_l, 1 << 20, 20, WinH + (size_t)l * 1048576, scales + l);
        cast_scale_kernel<<<dim3(512), blk, 0, stream>>>(
            Wout_l, 1 << 19, 19, WoutH + (size_t)l * 524288, scales + 3 + l);
        cast_scale_kernel<<<dim3(64), blk, 0, stream>>>(
            Wx_l, 1 << 16, 16, WxH + (size_t)l * 65536, scales + 7 + l);
    }
    amax_kernel<<<dim3(64), blk, 0, stream>>>(Wo, 16384, scales + 6);
    cast_scale_kernel<<<dim3(64), blk, 0, stream>>>(Wo, 1 << 16, 16, WoH, scales + 6);

    for (int c = 0; c < BB_ / CB; ++c) {
        const float* x_c = x + (size_t)c * Mc * DIN_;
        float* out_c     = out + (size_t)c * Mc * DOUT_;
        float* hbuf      = xz + 1024;    // h lives in dead z-half, ld 2048

        hipMemsetAsync(scales + 10, 0, 10 * sizeof(unsigned int), stream);

        // h = x @ Wi.T + bi  (fp32, K=64) -> xz[:,1024:1536], amax -> h[0]
        gemm_t128<1><<<dim3(D_ / 128, rowTiles), blk, 0, stream>>>(
            x_c, DIN_, Wi, DIN_, bi, hbuf, 2048, DIN_, scales + 10);

        for (int l = 0; l < L_; ++l) {
            const float* cw_l   = convw + (size_t)l * DI_ * DC_;
            const float* cb_l   = convb + (size_t)l * DI_;
            const float* Wdt_l  = Wdt  + (size_t)l * DI_ * R_;
            const float* bdt_l  = bdt  + (size_t)l * DI_;
            const float* Alog_l = A_log + (size_t)l * DI_ * N_;
            const float* Dp_l   = Dp   + (size_t)l * DI_;

            // Ah = f16(h)  (strided: width 512, ld 2048)
            cast_scale_kernel<<<dim3((unsigned)(Mc * 512 / 1024)), blk, 0, stream>>>(
                hbuf, 2048, 9, Ah, scales + 10 + l);

            // xz = h @ Win.T  (f16 MFMA, pipelined)
            gemm_f16_t128<0><<<dim3(2048 / 128, rowTiles), blk, 0, stream>>>(
                Ah, D_, WinH + (size_t)l * 1048576, D_, nullptr,
                xz, 2048, D_, scales + 10 + l, scales + l, nullptr);

            // u = silu(causal_dwconv(xin) + cb)
            conv_silu_kernel<<<dim3((unsigned)(Mc * DI_ / 256)), blk, 0, stream>>>(
                xz, cw_l, cb_l, u);

            // u amax + f16 cast into Ah (h f16 is dead after xz GEMM)
            amax_kernel<<<dim3(1024), blk, 0, stream>>>(u, Mc * 256, scales + 17 + l);
            cast_scale_kernel<<<dim3((unsigned)(Mc * 1024 / 1024)), blk, 0, stream>>>(
                u, 1024, 10, Ah, scales + 17 + l);

            // dbc = u @ Wx.T  (f16 MFMA, 128x64 tile)
            gemm_f16_t64n<<<dim3(1, rowTiles), blk, 0, stream>>>(
                Ah, DI_, WxH + (size_t)l * 65536, DI_, dbc, 64, DI_,
                scales + 17 + l, scales + 7 + l);

            // delta = softplus(dt @ Wdt.T + bdt) -> xz[:, :1024] (ldc 2048)
            gemm_t128<2><<<dim3(DI_ / 128, rowTiles), blk, 0, stream>>>(
                dbc, 64, Wdt_l, R_, bdt_l, xz, 2048, R_, nullptr);

            // chunk-parallel scan; g -> xz[:, :1024], amax -> g[l]
            scan_pass1<<<dim3(CB, DI_ / 256, NCH_), blk, 0, stream>>>(
                xz, u, dbc, Alog_l, Pbuf, Sbuf);
            scan_carry<<<dim3(CB * 64), blk, 0, stream>>>(Pbuf, Sbuf);
            scan_pass3<<<dim3(CB, DI_ / 256, NCH_), blk, 0, stream>>>(
                xz, u, dbc, Alog_l, Dp_l, Sbuf, scales + 14 + l);

            // Ah = f16(g)  (strided: width 1024, ld 2048)
            cast_scale_kernel<<<dim3((unsigned)(Mc * 1024 / 1024)), blk, 0, stream>>>(
                xz, 2048, 10, Ah, scales + 14 + l);

            // h = g @ Wout.T  (f16 MFMA) -> xz[:,1024:1536], amax -> h[l+1]
            gemm_f16_t128<0><<<dim3(D_ / 128, rowTiles), blk, 0, stream>>>(
                Ah, DI_, WoutH + (size_t)l * 524288, DI_, nullptr,
                hbuf, 2048, DI_, scales + 14 + l, scales + 3 + l, scales + 11 + l);
        }

        // out = tanh(h @ Wo.T + bo)
        cast_scale_kernel<<<dim3((unsigned)(Mc * 512 / 1024)), blk, 0, stream>>>(
            hbuf, 2048, 9, Ah, scales + 13);
        gemm_f16_t128<3><<<dim3(DOUT_ / 128, rowTiles), blk, 0, stream>>>(
            Ah, D_, WoH, D_, bo, out_c, DOUT_, D_, scales + 13, scales + 6, nullptr);
    }
}

// Round 10
// 2973.988 us; speedup vs baseline: 6.9315x; 1.2036x over previous
//
#include <hip/hip_runtime.h>
#include <hip/hip_bf16.h>

#define BB_ 16
#define T_ 2048
#define DIN_ 64
#define D_ 512
#define DI_ 1024
#define N_ 16
#define DC_ 4
#define R_ 32
#define L_ 3
#define DOUT_ 128
#define CL_ 128              // scan chunk length
#define NCH_ (T_ / CL_)      // 16 chunks

typedef __attribute__((ext_vector_type(8))) _Float16 f16x8;
typedef __attribute__((ext_vector_type(4))) float f32x4;

__device__ __forceinline__ float silu_f(float x) { return x / (1.f + __expf(-x)); }

__device__ __forceinline__ unsigned short f2h(float f) {
    union { _Float16 h; unsigned short u; } c;
    c.h = (_Float16)f;   // RNE
    return c.u;
}

// decode scale from amax bits: s = 2^(11 - e), so s*amax lands in [2^11, 2^12)
__device__ __forceinline__ float decode_scale(unsigned int bits) {
    if (bits == 0u) return 1.f;
    const int E = (int)(bits >> 23) & 0xFF;
    return __uint_as_float((unsigned)(265 - E) << 23);
}

__device__ __forceinline__ uint4 pack8(float4 lo, float4 hi, float s) {
    union { uint4 u; unsigned short h[8]; } r;
    r.h[0] = f2h(lo.x * s); r.h[1] = f2h(lo.y * s);
    r.h[2] = f2h(lo.z * s); r.h[3] = f2h(lo.w * s);
    r.h[4] = f2h(hi.x * s); r.h[5] = f2h(hi.y * s);
    r.h[6] = f2h(hi.z * s); r.h[7] = f2h(hi.w * s);
    return r.u;
}

// region table: 0-2 Win[l] (n4=262144), 3-5 Wout[l] (131072), 6 Wo (16384),
// 7-9 Wx[l] (16384). slot == region.
__device__ __forceinline__ void wregion(
    int r, const float* Win, const float* Wout, const float* Wx, const float* Wo,
    const float** p, size_t* n4, int* slot)
{
    if (r < 3)      { *p = Win  + (size_t)r * 1048576;      *n4 = 262144; }
    else if (r < 6) { *p = Wout + (size_t)(r - 3) * 524288; *n4 = 131072; }
    else if (r == 6){ *p = Wo;                               *n4 = 16384;  }
    else            { *p = Wx   + (size_t)(r - 7) * 65536;  *n4 = 16384;  }
    *slot = r;
}

// all-weights absmax: one kernel, grid.z = region
__global__ __launch_bounds__(256) void amax_all(
    const float* __restrict__ Win, const float* __restrict__ Wout,
    const float* __restrict__ Wx, const float* __restrict__ Wo,
    unsigned int* __restrict__ scales)
{
    const float* p; size_t n4; int slot;
    wregion(blockIdx.z, Win, Wout, Wx, Wo, &p, &n4, &slot);
    float m = 0.f;
    for (size_t i = (size_t)blockIdx.x * 256 + threadIdx.x; i < n4;
         i += (size_t)gridDim.x * 256) {
        const float4 v = ((const float4*)p)[i];
        m = fmaxf(m, fmaxf(fmaxf(fabsf(v.x), fabsf(v.y)),
                           fmaxf(fabsf(v.z), fabsf(v.w))));
    }
#pragma unroll
    for (int off = 32; off; off >>= 1) m = fmaxf(m, __shfl_down(m, off));
    __shared__ float sm[4];
    if ((threadIdx.x & 63) == 0) sm[threadIdx.x >> 6] = m;
    __syncthreads();
    if (threadIdx.x == 0) {
        const float b = fmaxf(fmaxf(sm[0], sm[1]), fmaxf(sm[2], sm[3]));
        atomicMax(scales + slot, __float_as_uint(b));
    }
}

// all-weights scaled f16 cast: grid.z = region
__global__ __launch_bounds__(256) void cast_all(
    const float* __restrict__ Win, const float* __restrict__ Wout,
    const float* __restrict__ Wx, const float* __restrict__ Wo,
    unsigned short* __restrict__ WinH, unsigned short* __restrict__ WoutH,
    unsigned short* __restrict__ WxH, unsigned short* __restrict__ WoH,
    const unsigned int* __restrict__ scales)
{
    const int r = blockIdx.z;
    const float* p; size_t n4; int slot;
    wregion(r, Win, Wout, Wx, Wo, &p, &n4, &slot);
    unsigned short* o;
    if (r < 3)       o = WinH  + (size_t)r * 1048576;
    else if (r < 6)  o = WoutH + (size_t)(r - 3) * 524288;
    else if (r == 6) o = WoH;
    else             o = WxH   + (size_t)(r - 7) * 65536;
    const float s = decode_scale(scales[slot]);
    for (size_t i = (size_t)blockIdx.x * 256 + threadIdx.x; i < n4;
         i += (size_t)gridDim.x * 256) {
        const float4 v = ((const float4*)p)[i];
        ((ushort4*)o)[i] = make_ushort4(f2h(v.x * s), f2h(v.y * s),
                                        f2h(v.z * s), f2h(v.w * s));
    }
}

// fp32 -> f16 scaled cast over rows: element (m, col) with col < 2^shift,
// row stride ldin. Output contiguous (m << shift) + col.
__global__ __launch_bounds__(256) void cast_scale_kernel(
    const float* __restrict__ in, int ldin, int shift,
    unsigned short* __restrict__ out, const unsigned int* __restrict__ slot)
{
    const float s = decode_scale(*slot);
    const size_t gid4 = ((size_t)blockIdx.x * 256 + threadIdx.x) * 4;
    const size_t m = gid4 >> shift;
    const int col = (int)(gid4 & ((1u << shift) - 1));
    const float4 v = *(const float4*)(in + m * ldin + col);
    *(ushort4*)(out + gid4) = make_ushort4(f2h(v.x * s), f2h(v.y * s),
                                           f2h(v.z * s), f2h(v.w * s));
}

// ---------------- scaled f16 MFMA GEMM: C = (A @ B^T) * inv ----------------
// 128x128 tile, BK=32, 4 waves (2x2), per-wave 64x64 = 4x4 frags of 16x16x32.
// Software-pipelined: global loads for step k+1 issued before MFMA of step k.
// ACT: 0 = none, 3 = +bias then tanh. Output fp32 (+ optional amax slot).
template<int ACT>
__global__ __launch_bounds__(256) void gemm_f16_t128(
    const unsigned short* __restrict__ A, int lda,
    const unsigned short* __restrict__ B, int ldb,
    const float* __restrict__ bias,
    float* __restrict__ C, int ldc, int K,
    const unsigned int* __restrict__ sa, const unsigned int* __restrict__ sb,
    unsigned int* __restrict__ oamax)
{
    __shared__ __align__(16) unsigned short As[128 * 32];
    __shared__ __align__(16) unsigned short Bs[128 * 32];
    const int tid  = threadIdx.x;
    const int lane = tid & 63;
    const int w    = tid >> 6;
    const int wr   = (w >> 1) << 6;
    const int wc   = (w & 1) << 6;
    const int l15  = lane & 15, l4 = lane >> 4;
    const int row0 = blockIdx.y << 7, col0 = blockIdx.x << 7;
    const int tq   = tid >> 2;
    const int tr   = (tid & 3) << 3;

    const float inv = (1.f / decode_scale(*sa)) * (1.f / decode_scale(*sb));

    const unsigned short* Ar0 = A + (size_t)(row0 + tq) * lda + tr;
    const unsigned short* Ar1 = A + (size_t)(row0 + 64 + tq) * lda + tr;
    const unsigned short* Br0 = B + (size_t)(col0 + tq) * ldb + tr;
    const unsigned short* Br1 = B + (size_t)(col0 + 64 + tq) * ldb + tr;

    f32x4 acc[4][4];
#pragma unroll
    for (int m = 0; m < 4; ++m)
#pragma unroll
        for (int n = 0; n < 4; ++n) acc[m][n] = (f32x4){0.f, 0.f, 0.f, 0.f};

    uint4 av0 = *(const uint4*)(Ar0);
    uint4 av1 = *(const uint4*)(Ar1);
    uint4 bv0 = *(const uint4*)(Br0);
    uint4 bv1 = *(const uint4*)(Br1);

    for (int k0 = 0; k0 < K; k0 += 32) {
        __syncthreads();
        *(uint4*)&As[tq * 32 + tr]        = av0;
        *(uint4*)&As[(64 + tq) * 32 + tr] = av1;
        *(uint4*)&Bs[tq * 32 + tr]        = bv0;
        *(uint4*)&Bs[(64 + tq) * 32 + tr] = bv1;
        __syncthreads();

        if (k0 + 32 < K) {   // issue next-step loads; waited at next ds_write
            av0 = *(const uint4*)(Ar0 + k0 + 32);
            av1 = *(const uint4*)(Ar1 + k0 + 32);
            bv0 = *(const uint4*)(Br0 + k0 + 32);
            bv1 = *(const uint4*)(Br1 + k0 + 32);
        }

        f16x8 af[4], bfr[4];
#pragma unroll
        for (int m = 0; m < 4; ++m)
            af[m] = *(const f16x8*)&As[(wr + m * 16 + l15) * 32 + l4 * 8];
#pragma unroll
        for (int n = 0; n < 4; ++n)
            bfr[n] = *(const f16x8*)&Bs[(wc + n * 16 + l15) * 32 + l4 * 8];
#pragma unroll
        for (int m = 0; m < 4; ++m)
#pragma unroll
            for (int n = 0; n < 4; ++n)
                acc[m][n] = __builtin_amdgcn_mfma_f32_16x16x32_f16(
                    af[m], bfr[n], acc[m][n], 0, 0, 0);
    }

    float am = 0.f;
#pragma unroll
    for (int n = 0; n < 4; ++n) {
        const int col = col0 + wc + n * 16 + l15;
        float bc = 0.f;
        if (ACT == 3) bc = bias[col];
#pragma unroll
        for (int m = 0; m < 4; ++m) {
            const int rowb = row0 + wr + m * 16 + (l4 << 2);
#pragma unroll
            for (int r = 0; r < 4; ++r) {
                float v = acc[m][n][r] * inv;
                if (ACT == 3) v = tanhf(v + bc);
                C[(size_t)(rowb + r) * ldc + col] = v;
                am = fmaxf(am, fabsf(v));
            }
        }
    }
    if (oamax) {
#pragma unroll
        for (int off = 32; off; off >>= 1) am = fmaxf(am, __shfl_down(am, off));
        if (lane == 0) atomicMax(oamax, __float_as_uint(am));
    }
}

// ---- dbc GEMM: A is fp32 u (cast-with-scale during LDS staging), B f16 ----
// 128x64 tile, 4 waves, wave w owns rows w*32 (2x16) x 64 cols. Pipelined.
__global__ __launch_bounds__(256) void gemm_f16u_t64n(
    const float* __restrict__ A, int lda,
    const unsigned short* __restrict__ B, int ldb,
    float* __restrict__ C, int ldc, int K,
    const unsigned int* __restrict__ sa, const unsigned int* __restrict__ sb)
{
    __shared__ __align__(16) unsigned short As[128 * 32];
    __shared__ __align__(16) unsigned short Bs[64 * 32];
    const int tid  = threadIdx.x;
    const int lane = tid & 63;
    const int w    = tid >> 6;
    const int l15  = lane & 15, l4 = lane >> 4;
    const int row0 = blockIdx.y << 7;
    const int tq   = tid >> 2;
    const int tr   = (tid & 3) << 3;

    const float sA  = decode_scale(*sa);
    const float inv = (1.f / sA) * (1.f / decode_scale(*sb));

    const float* Ar0 = A + (size_t)(row0 + tq) * lda + tr;
    const float* Ar1 = A + (size_t)(row0 + 64 + tq) * lda + tr;
    const unsigned short* Br = B + (size_t)tq * ldb + tr;   // 64 rows

    f32x4 acc[2][4];
#pragma unroll
    for (int m = 0; m < 2; ++m)
#pragma unroll
        for (int n = 0; n < 4; ++n) acc[m][n] = (f32x4){0.f, 0.f, 0.f, 0.f};

    float4 a0lo = *(const float4*)(Ar0),     a0hi = *(const float4*)(Ar0 + 4);
    float4 a1lo = *(const float4*)(Ar1),     a1hi = *(const float4*)(Ar1 + 4);
    uint4  bv   = *(const uint4*)(Br);

    for (int k0 = 0; k0 < K; k0 += 32) {
        __syncthreads();
        *(uint4*)&As[tq * 32 + tr]        = pack8(a0lo, a0hi, sA);
        *(uint4*)&As[(64 + tq) * 32 + tr] = pack8(a1lo, a1hi, sA);
        *(uint4*)&Bs[tq * 32 + tr]        = bv;
        __syncthreads();

        if (k0 + 32 < K) {
            a0lo = *(const float4*)(Ar0 + k0 + 32);
            a0hi = *(const float4*)(Ar0 + k0 + 36);
            a1lo = *(const float4*)(Ar1 + k0 + 32);
            a1hi = *(const float4*)(Ar1 + k0 + 36);
            bv   = *(const uint4*)(Br  + k0 + 32);
        }

        f16x8 af[2], bfr[4];
#pragma unroll
        for (int m = 0; m < 2; ++m)
            af[m] = *(const f16x8*)&As[(w * 32 + m * 16 + l15) * 32 + l4 * 8];
#pragma unroll
        for (int n = 0; n < 4; ++n)
            bfr[n] = *(const f16x8*)&Bs[(n * 16 + l15) * 32 + l4 * 8];
#pragma unroll
        for (int m = 0; m < 2; ++m)
#pragma unroll
            for (int n = 0; n < 4; ++n)
                acc[m][n] = __builtin_amdgcn_mfma_f32_16x16x32_f16(
                    af[m], bfr[n], acc[m][n], 0, 0, 0);
    }

#pragma unroll
    for (int n = 0; n < 4; ++n) {
        const int col = n * 16 + l15;
#pragma unroll
        for (int m = 0; m < 2; ++m) {
            const int rowb = row0 + w * 32 + m * 16 + (l4 << 2);
#pragma unroll
            for (int r = 0; r < 4; ++r)
                C[(size_t)(rowb + r) * ldc + col] = acc[m][n][r] * inv;
        }
    }
}

// ---------------- fp32 vector GEMM (small-K shapes) ----------------
// ACT: 1 +bias, 2 +bias softplus.
template<int ACT>
__global__ __launch_bounds__(256) void gemm_t128(
    const float* __restrict__ A, int lda,
    const float* __restrict__ B, int ldb,
    const float* __restrict__ bias,
    float* __restrict__ C, int ldc, int K,
    unsigned int* __restrict__ oamax)
{
    __shared__ __align__(16) float As[8][128];
    __shared__ __align__(16) float Bs[8][128];
    const int tid  = threadIdx.x;
    const int row0 = blockIdx.y << 7;
    const int col0 = blockIdx.x << 7;
    const int tx = tid & 15, ty = tid >> 4;

    float acc[8][8];
#pragma unroll
    for (int i = 0; i < 8; ++i)
#pragma unroll
        for (int j = 0; j < 8; ++j) acc[i][j] = 0.f;

    const int arow = tid >> 1;
    const int acol = (tid & 1) << 2;
    const float* Ap = A + (size_t)(row0 + arow) * lda + acol;
    const float* Bp = B + (size_t)(col0 + arow) * ldb + acol;

    for (int k0 = 0; k0 < K; k0 += 8) {
        const float4 av = *(const float4*)(Ap + k0);
        const float4 bv = *(const float4*)(Bp + k0);
        __syncthreads();
        As[acol + 0][arow] = av.x; As[acol + 1][arow] = av.y;
        As[acol + 2][arow] = av.z; As[acol + 3][arow] = av.w;
        Bs[acol + 0][arow] = bv.x; Bs[acol + 1][arow] = bv.y;
        Bs[acol + 2][arow] = bv.z; Bs[acol + 3][arow] = bv.w;
        __syncthreads();
#pragma unroll
        for (int k = 0; k < 8; ++k) {
            float a[8], b[8];
            *(float4*)&a[0] = *(const float4*)&As[k][ty << 3];
            *(float4*)&a[4] = *(const float4*)&As[k][(ty << 3) + 4];
            *(float4*)&b[0] = *(const float4*)&Bs[k][tx << 3];
            *(float4*)&b[4] = *(const float4*)&Bs[k][(tx << 3) + 4];
#pragma unroll
            for (int i = 0; i < 8; ++i)
#pragma unroll
                for (int j = 0; j < 8; ++j)
                    acc[i][j] = fmaf(a[i], b[j], acc[i][j]);
        }
    }

    float bv8[8];
#pragma unroll
    for (int j = 0; j < 8; ++j) bv8[j] = (ACT >= 1) ? bias[col0 + (tx << 3) + j] : 0.f;

    float am = 0.f;
#pragma unroll
    for (int i = 0; i < 8; ++i) {
        float v[8];
#pragma unroll
        for (int j = 0; j < 8; ++j) {
            float t = (ACT >= 1) ? (acc[i][j] + bv8[j]) : acc[i][j];
            if (ACT == 2) t = (t > 20.f) ? t : log1pf(__expf(t));
            v[j] = t;
            am = fmaxf(am, fabsf(t));
        }
        float* Cp = C + (size_t)(row0 + (ty << 3) + i) * ldc + col0 + (tx << 3);
        *(float4*)(Cp)     = make_float4(v[0], v[1], v[2], v[3]);
        *(float4*)(Cp + 4) = make_float4(v[4], v[5], v[6], v[7]);
    }
    if (oamax) {
#pragma unroll
        for (int off = 32; off; off >>= 1) am = fmaxf(am, __shfl_down(am, off));
        if ((tid & 63) == 0) atomicMax(oamax, __float_as_uint(am));
    }
}

// depthwise causal conv (DC=4) + bias + SiLU, grid-stride, fused u amax.
__global__ __launch_bounds__(256) void conv_silu_kernel(
    const float* __restrict__ xz, const float* __restrict__ cw,
    const float* __restrict__ cb, float* __restrict__ u,
    size_t total, unsigned int* __restrict__ uamax)
{
    float am = 0.f;
    for (size_t idx = (size_t)blockIdx.x * 256 + threadIdx.x; idx < total;
         idx += (size_t)gridDim.x * 256) {
        const int c = (int)(idx & (DI_ - 1));
        const size_t m = idx >> 10;
        const int t = (int)(m & (T_ - 1));
        const float w0 = cw[c * DC_ + 0], w1 = cw[c * DC_ + 1];
        const float w2 = cw[c * DC_ + 2], w3 = cw[c * DC_ + 3];
        const float* xr = xz + m * 2048 + c;
        float acc = cb[c];
        if (t >= 3) acc = fmaf(xr[-3 * 2048], w0, acc);
        if (t >= 2) acc = fmaf(xr[-2 * 2048], w1, acc);
        if (t >= 1) acc = fmaf(xr[-1 * 2048], w2, acc);
        acc = fmaf(xr[0], w3, acc);
        const float uv = silu_f(acc);
        u[idx] = uv;
        am = fmaxf(am, fabsf(uv));
    }
#pragma unroll
    for (int off = 32; off; off >>= 1) am = fmaxf(am, __shfl_down(am, off));
    __shared__ float sm[4];
    if ((threadIdx.x & 63) == 0) sm[threadIdx.x >> 6] = am;
    __syncthreads();
    if (threadIdx.x == 0) {
        const float b = fmaxf(fmaxf(sm[0], sm[1]), fmaxf(sm[2], sm[3]));
        atomicMax(uamax, __float_as_uint(b));
    }
}

// -------- chunk-parallel selective scan (linear recurrence, 3 phases) -----
// State per (b,d): 16 values. delta at xz[m*2048+d], z at xz[m*2048+1024+d].
// P/S layout: idx(b,ch,n,d) = (((b*NCH+ch)*N + n) << 10) + d.
// Fast path: if a2[n] == (n+1)*a2[0] (A_log = log(1..N) tile), dA_n = r^(n+1)
// with one exp2 per step instead of 16.

__device__ __forceinline__ bool geo_check(const float* a2) {
    bool ok = true;
#pragma unroll
    for (int n = 1; n < N_; ++n)
        ok = ok && (fabsf(a2[n] - a2[0] * (n + 1)) <=
                    1e-5f * fmaxf(1.f, fabsf(a2[n])));
    return ok;
}

__global__ __launch_bounds__(256) void scan_pass1(
    const float* __restrict__ xz, const float* __restrict__ u,
    const float* __restrict__ dbc, const float* __restrict__ A_log_l,
    float* __restrict__ P, float* __restrict__ S)
{
    __shared__ float sB[CL_][N_];
    const int tid = threadIdx.x;
    const int b = blockIdx.x, ch = blockIdx.z;
    const int d = (blockIdx.y << 8) + tid;

    float a2[N_], Pm[N_], hs[N_];
#pragma unroll
    for (int n = 0; n < N_; ++n) {
        a2[n] = -__expf(A_log_l[d * N_ + n]) * 1.44269504f;
        Pm[n] = 1.f; hs[n] = 0.f;
    }
    const bool geo = geo_check(a2);
    for (int i = tid; i < CL_ * N_; i += 256) {
        const int tl = i >> 4, n = i & 15;
        sB[tl][n] = dbc[((size_t)b * T_ + ch * CL_ + tl) * 64 + 32 + n];
    }
    __syncthreads();

    if (geo) {
        for (int tt = 0; tt < CL_; ++tt) {
            const size_t m = (size_t)b * T_ + ch * CL_ + tt;
            const float dl = xz[m * 2048 + d];
            const float du = dl * u[m * DI_ + d];
            const float r = exp2f(dl * a2[0]);
            float dA = r;
#pragma unroll
            for (int n = 0; n < N_; ++n) {
                Pm[n] *= dA;
                hs[n] = fmaf(dA, hs[n], du * sB[tt][n]);
                dA *= r;
            }
        }
    } else {
        for (int tt = 0; tt < CL_; ++tt) {
            const size_t m = (size_t)b * T_ + ch * CL_ + tt;
            const float dl = xz[m * 2048 + d];
            const float du = dl * u[m * DI_ + d];
#pragma unroll
            for (int n = 0; n < N_; ++n) {
                const float dA = exp2f(dl * a2[n]);
                Pm[n] *= dA;
                hs[n] = fmaf(dA, hs[n], du * sB[tt][n]);
            }
        }
    }
#pragma unroll
    for (int n = 0; n < N_; ++n) {
        const size_t idx = (size_t)(((b * NCH_ + ch) * N_ + n) << 10) + d;
        P[idx] = Pm[n]; S[idx] = hs[n];
    }
}

// carry: per (b,n,d) combine chunks sequentially; S[ch] becomes h_init(ch).
__global__ __launch_bounds__(256) void scan_carry(
    const float* __restrict__ P, float* __restrict__ S)
{
    const size_t gid = (size_t)blockIdx.x * 256 + threadIdx.x;
    const int d = (int)(gid & 1023);
    const int n = (int)((gid >> 10) & 15);
    const int b = (int)(gid >> 14);
    float hc = 0.f;
    for (int ch = 0; ch < NCH_; ++ch) {
        const size_t idx = (size_t)(((b * NCH_ + ch) * N_ + n) << 10) + d;
        const float p = P[idx], s = S[idx];
        S[idx] = hc;
        hc = fmaf(p, hc, s);
    }
}

// pass3: redo in-chunk scan from h_init, emit g = (y + u*Dp)*silu(z) over
// the delta slot; track amax(g) -> slot.
__global__ __launch_bounds__(256) void scan_pass3(
    float* __restrict__ xz, const float* __restrict__ u,
    const float* __restrict__ dbc, const float* __restrict__ A_log_l,
    const float* __restrict__ Dp_l, const float* __restrict__ S,
    unsigned int* __restrict__ gmax)
{
    __shared__ float sB[CL_][N_];
    __shared__ float sC[CL_][N_];
    const int tid = threadIdx.x;
    const int b = blockIdx.x, ch = blockIdx.z;
    const int d = (blockIdx.y << 8) + tid;

    float a2[N_], hs[N_];
#pragma unroll
    for (int n = 0; n < N_; ++n) {
        a2[n] = -__expf(A_log_l[d * N_ + n]) * 1.44269504f;
        hs[n] = S[(size_t)(((b * NCH_ + ch) * N_ + n) << 10) + d];
    }
    const bool geo = geo_check(a2);
    const float Dpd = Dp_l[d];
    for (int i = tid; i < CL_ * N_; i += 256) {
        const int tl = i >> 4, n = i & 15;
        const size_t base = ((size_t)b * T_ + ch * CL_ + tl) * 64;
        sB[tl][n] = dbc[base + 32 + n];
        sC[tl][n] = dbc[base + 48 + n];
    }
    __syncthreads();

    float gm = 0.f;
    if (geo) {
        for (int tt = 0; tt < CL_; ++tt) {
            const size_t m = (size_t)b * T_ + ch * CL_ + tt;
            const float dl = xz[m * 2048 + d];
            const float uv = u[m * DI_ + d];
            const float du = dl * uv;
            const float r = exp2f(dl * a2[0]);
            float dA = r;
            float yv = 0.f;
#pragma unroll
            for (int n = 0; n < N_; ++n) {
                hs[n] = fmaf(dA, hs[n], du * sB[tt][n]);
                yv = fmaf(hs[n], sC[tt][n], yv);
                dA *= r;
            }
            yv = fmaf(uv, Dpd, yv);
            const float g = yv * silu_f(xz[m * 2048 + DI_ + d]);
            xz[m * 2048 + d] = g;
            gm = fmaxf(gm, fabsf(g));
        }
    } else {
        for (int tt = 0; tt < CL_; ++tt) {
            const size_t m = (size_t)b * T_ + ch * CL_ + tt;
            const float dl = xz[m * 2048 + d];
            const float uv = u[m * DI_ + d];
            const float du = dl * uv;
            float yv = 0.f;
#pragma unroll
            for (int n = 0; n < N_; ++n) {
                const float dA = exp2f(dl * a2[n]);
                hs[n] = fmaf(dA, hs[n], du * sB[tt][n]);
                yv = fmaf(hs[n], sC[tt][n], yv);
            }
            yv = fmaf(uv, Dpd, yv);
            const float g = yv * silu_f(xz[m * 2048 + DI_ + d]);
            xz[m * 2048 + d] = g;
            gm = fmaxf(gm, fabsf(g));
        }
    }
#pragma unroll
    for (int off = 32; off; off >>= 1) gm = fmaxf(gm, __shfl_down(gm, off));
    if ((tid & 63) == 0) atomicMax(gmax, __float_as_uint(gm));
}

extern "C" void kernel_launch(void* const* d_in, const int* in_sizes, int n_in,
                              void* d_out, int out_size, void* d_ws, size_t ws_size,
                              hipStream_t stream) {
    const float* x     = (const float*)d_in[0];
    const float* Wi    = (const float*)d_in[1];
    const float* bi    = (const float*)d_in[2];
    const float* Win   = (const float*)d_in[3];
    const float* convw = (const float*)d_in[4];
    const float* convb = (const float*)d_in[5];
    const float* Wx    = (const float*)d_in[6];
    const float* Wdt   = (const float*)d_in[7];
    const float* bdt   = (const float*)d_in[8];
    const float* A_log = (const float*)d_in[9];
    const float* Dp    = (const float*)d_in[10];
    const float* Wout  = (const float*)d_in[11];
    const float* Wo    = (const float*)d_in[12];
    const float* bo    = (const float*)d_in[13];
    float* out = (float*)d_out;

    // Per-row f32: xz 2048 + u 1024 + dbc 64 + AhF 512 (Ah f16 / scan P,S) = 3648.
    // Extras: f16 weights (3 Win + 3 Wout + Wo + 3 Wx) + 32 scale slots.
    const size_t rowf = 3648;
    const size_t wextra = (3 * 1048576 + 3 * 524288 + 65536 + 3 * 65536) / 2 + 32;
    int CB = BB_;
    while (CB > 1 && ((size_t)CB * T_ * rowf + wextra) * sizeof(float) > ws_size) CB >>= 1;
    const size_t Mc = (size_t)CB * T_;

    const dim3 blk(256);
    const int rowTiles = (int)(Mc / 128);

    float* ws   = (float*)d_ws;
    float* xz   = ws;                    // Mc*2048 (xin/delta/g | z+h)
    float* u    = xz + Mc * 2048;        // Mc*1024
    float* dbc  = u  + Mc * 1024;        // Mc*64
    float* AhF  = dbc + Mc * 64;         // Mc*512 f32 (= Mc*1024 ushorts)
    unsigned short* Ah = (unsigned short*)AhF;
    float* Pbuf = AhF;                               // CB*NCH*N*DI floats
    float* Sbuf = AhF + (size_t)CB * NCH_ * N_ * DI_;
    unsigned short* WinH  = (unsigned short*)(AhF + Mc * 512);
    unsigned short* WoutH = WinH + 3 * 1048576;
    unsigned short* WoH   = WoutH + 3 * 524288;
    unsigned short* WxH   = WoH + 65536;
    unsigned int* scales  = (unsigned int*)(WxH + 3 * 65536);
    // slots: 0-2 Win[l], 3-5 Wout[l], 6 Wo, 7-9 Wx[l],
    //        10..13 h[0..3], 14..16 g[l], 17..19 u[l]

    hipMemsetAsync(scales, 0, 32 * sizeof(unsigned int), stream);

    // ---- weight amax + f16 casts (2 kernels, region table over grid.z) ----
    amax_all<<<dim3(128, 1, 10), blk, 0, stream>>>(Win, Wout, Wx, Wo, scales);
    cast_all<<<dim3(64, 1, 10), blk, 0, stream>>>(
        Win, Wout, Wx, Wo, WinH, WoutH, WxH, WoH, scales);

    for (int c = 0; c < BB_ / CB; ++c) {
        const float* x_c = x + (size_t)c * Mc * DIN_;
        float* out_c     = out + (size_t)c * Mc * DOUT_;
        float* hbuf      = xz + 1024;    // h lives in dead z-half, ld 2048

        hipMemsetAsync(scales + 10, 0, 10 * sizeof(unsigned int), stream);

        // h = x @ Wi.T + bi  (fp32, K=64) -> xz[:,1024:1536], amax -> h[0]
        gemm_t128<1><<<dim3(D_ / 128, rowTiles), blk, 0, stream>>>(
            x_c, DIN_, Wi, DIN_, bi, hbuf, 2048, DIN_, scales + 10);

        for (int l = 0; l < L_; ++l) {
            const float* cw_l   = convw + (size_t)l * DI_ * DC_;
            const float* cb_l   = convb + (size_t)l * DI_;
            const float* Wdt_l  = Wdt  + (size_t)l * DI_ * R_;
            const float* bdt_l  = bdt  + (size_t)l * DI_;
            const float* Alog_l = A_log + (size_t)l * DI_ * N_;
            const float* Dp_l   = Dp   + (size_t)l * DI_;

            // Ah = f16(h)  (strided: width 512, ld 2048)
            cast_scale_kernel<<<dim3((unsigned)(Mc * 512 / 1024)), blk, 0, stream>>>(
                hbuf, 2048, 9, Ah, scales + 10 + l);

            // xz = h @ Win.T  (f16 MFMA, pipelined)
            gemm_f16_t128<0><<<dim3(2048 / 128, rowTiles), blk, 0, stream>>>(
                Ah, D_, WinH + (size_t)l * 1048576, D_, nullptr,
                xz, 2048, D_, scales + 10 + l, scales + l, nullptr);

            // u = silu(causal_dwconv(xin) + cb), fused u amax -> u[l]
            conv_silu_kernel<<<dim3(2048), blk, 0, stream>>>(
                xz, cw_l, cb_l, u, Mc * DI_, scales + 17 + l);

            // dbc = u(fp32, staged-cast) @ Wx.T  (f16 MFMA, 128x64 tile)
            gemm_f16u_t64n<<<dim3(1, rowTiles), blk, 0, stream>>>(
                u, DI_, WxH + (size_t)l * 65536, DI_, dbc, 64, DI_,
                scales + 17 + l, scales + 7 + l);

            // delta = softplus(dt @ Wdt.T + bdt) -> xz[:, :1024] (ldc 2048)
            gemm_t128<2><<<dim3(DI_ / 128, rowTiles), blk, 0, stream>>>(
                dbc, 64, Wdt_l, R_, bdt_l, xz, 2048, R_, nullptr);

            // chunk-parallel scan; g -> xz[:, :1024], amax -> g[l]
            scan_pass1<<<dim3(CB, DI_ / 256, NCH_), blk, 0, stream>>>(
                xz, u, dbc, Alog_l, Pbuf, Sbuf);
            scan_carry<<<dim3(CB * 64), blk, 0, stream>>>(Pbuf, Sbuf);
            scan_pass3<<<dim3(CB, DI_ / 256, NCH_), blk, 0, stream>>>(
                xz, u, dbc, Alog_l, Dp_l, Sbuf, scales + 14 + l);

            // Ah = f16(g)  (strided: width 1024, ld 2048)
            cast_scale_kernel<<<dim3((unsigned)(Mc * 1024 / 1024)), blk, 0, stream>>>(
                xz, 2048, 10, Ah, scales + 14 + l);

            // h = g @ Wout.T  (f16 MFMA) -> xz[:,1024:1536], amax -> h[l+1]
            gemm_f16_t128<0><<<dim3(D_ / 128, rowTiles), blk, 0, stream>>>(
                Ah, DI_, WoutH + (size_t)l * 524288, DI_, nullptr,
                hbuf, 2048, DI_, scales + 14 + l, scales + 3 + l, scales + 11 + l);
        }

        // out = tanh(h @ Wo.T + bo)
        cast_scale_kernel<<<dim3((unsigned)(Mc * 512 / 1024)), blk, 0, stream>>>(
            hbuf, 2048, 9, Ah, scales + 13);
        gemm_f16_t128<3><<<dim3(DOUT_ / 128, rowTiles), blk, 0, stream>>>(
            Ah, D_, WoH, D_, bo, out_c, DOUT_, D_, scales + 13, scales + 6, nullptr);
    }
}